// Round 7
// baseline (136.205 us; speedup 1.0000x reference)
//
#include <hip/hip_runtime.h>
#include <hip/hip_bf16.h>

#define N_CELLS 128
#define C_N     256
#define K_NB    16
#define D_N     64
#define G_N     8
#define HS      128
#define HM      128
#define HMOD    64

typedef __bf16 bf16x8 __attribute__((ext_vector_type(8)));
typedef float  f32x4v __attribute__((ext_vector_type(4)));
typedef _Float16 half2_t __attribute__((ext_vector_type(2)));

// ---------- helpers ----------

__device__ __forceinline__ unsigned cvtpk(float lo, float hi) {
    __hip_bfloat162 t = __float22bfloat162_rn(float2{lo, hi});
    return *reinterpret_cast<unsigned*>(&t);
}

__device__ __forceinline__ unsigned short f2bf(float f) {
    return (unsigned short)(cvtpk(f, 0.f) & 0xffffu);
}

__device__ __forceinline__ float bflo(unsigned u) { return __uint_as_float(u << 16); }
__device__ __forceinline__ float bfhi(unsigned u) { return __uint_as_float(u & 0xffff0000u); }

__device__ __forceinline__ half2_t pkrtz(float lo, float hi) {
    return __builtin_bit_cast(half2_t, __builtin_amdgcn_cvt_pkrtz(lo, hi));
}

__device__ __forceinline__ f32x4v mfma16(uint4 a, uint4 b, f32x4v c) {
    return __builtin_amdgcn_mfma_f32_16x16x32_bf16(
        __builtin_bit_cast(bf16x8, a), __builtin_bit_cast(bf16x8, b), c, 0, 0, 0);
}

__device__ __forceinline__ float gelu_f(float x) {      // exact tanh-gelu (node/state)
    float x2 = x * x;
    float u  = x * fmaf(x2, 0.044715f, 1.0f);
    float e  = __expf(1.5957691216057308f * u);
    float r  = __builtin_amdgcn_rcpf(e + 1.0f);
    return x - x * r;
}

__device__ __forceinline__ float sgelu(float x) {       // sigmoid-gelu (edge): x*sigma(1.702x)
    float e = __expf(-1.702f * x);
    float r = __builtin_amdgcn_rcpf(e + 1.0f);
    return x * r;
}

__device__ __forceinline__ float tanh_fast(float z) {
    float e = __expf(2.0f * z);
    return 1.0f - 2.0f / (e + 1.0f);
}

__device__ __forceinline__ uint4 packf8(const float* p) {
    float4 a = *(const float4*)p, b = *(const float4*)(p + 4);
    return make_uint4(cvtpk(a.x, a.y), cvtpk(a.z, a.w), cvtpk(b.x, b.y), cvtpk(b.z, b.w));
}

// wf = gs2[d] * w2[d][k] * gs1[k];  c2 = gs2*(w2.gb1 + b2) + gb2   (verified R2)
__device__ __forceinline__ void load_w2_folded(
    const float* __restrict__ w2, const float* __restrict__ gs1,
    const float* __restrict__ gb1, const float* __restrict__ gs2,
    const float* __restrict__ b2, const float* __restrict__ gb2,
    int g, int lrow, int lgrp, uint4 wf[4][4], float c2[4])
{
    #pragma unroll
    for (int nb2 = 0; nb2 < 4; ++nb2) {
        int d = nb2 * 16 + lrow;
        float gs2d = gs2[g * 64 + d];
        float cgb = 0.0f;
        #pragma unroll
        for (int kf = 0; kf < 4; ++kf) {
            int k0 = kf * 32 + lgrp * 8;
            const float* wp = w2 + d * 128 + k0;
            float4 wa = *(const float4*)wp, wb = *(const float4*)(wp + 4);
            const float* gp = gs1 + g * 128 + k0;
            float4 ga = *(const float4*)gp, gbv = *(const float4*)(gp + 4);
            const float* bp = gb1 + g * 128 + k0;
            float4 ba = *(const float4*)bp, bbv = *(const float4*)(bp + 4);
            cgb += wa.x*ba.x + wa.y*ba.y + wa.z*ba.z + wa.w*ba.w
                 + wb.x*bbv.x + wb.y*bbv.y + wb.z*bbv.z + wb.w*bbv.w;
            wf[nb2][kf] = make_uint4(
                cvtpk(wa.x*ga.x*gs2d,  wa.y*ga.y*gs2d),
                cvtpk(wa.z*ga.z*gs2d,  wa.w*ga.w*gs2d),
                cvtpk(wb.x*gbv.x*gs2d, wb.y*gbv.y*gs2d),
                cvtpk(wb.z*gbv.z*gs2d, wb.w*gbv.w*gs2d));
        }
        cgb += __shfl_xor(cgb, 16);
        cgb += __shfl_xor(cgb, 32);
        c2[nb2] = fmaf(gs2d, cgb + b2[d], gb2[g * 64 + d]);
    }
}

// ---------- kernel 1: per-cell modulation gate ----------

__global__ __launch_bounds__(1024) void gate_kernel(
    const float* __restrict__ h,
    const float* __restrict__ mod_w1, const float* __restrict__ mod_b1,
    const float* __restrict__ mod_w2, const float* __restrict__ mod_b2,
    float* __restrict__ gatep)
{
    __shared__ float red[16][64];
    __shared__ float pooled[64];
    __shared__ float mh[64];
    int n = blockIdx.x, tid = threadIdx.x;
    int d = tid & 63, part = tid >> 6;
    const float* hn = h + (size_t)n * C_N * 64;
    float acc = 0.0f;
    #pragma unroll 4
    for (int i = 0; i < 16; ++i) acc += hn[(part * 16 + i) * 64 + d];
    red[part][d] = acc;
    __syncthreads();
    if (tid < 64) {
        float s = 0.0f;
        #pragma unroll
        for (int p = 0; p < 16; ++p) s += red[p][d];
        pooled[d] = s * (1.0f / 256.0f);
    }
    __syncthreads();
    if (tid < 64) {
        float a1 = mod_b1[n * HMOD + d];
        for (int q = 0; q < 64; ++q)
            a1 = fmaf(pooled[q], mod_w1[((size_t)n * 64 + q) * HMOD + d], a1);
        mh[d] = tanh_fast(a1);
    }
    __syncthreads();
    if (tid < 64) {
        float a2 = mod_b2[n * 64 + d];
        for (int q = 0; q < HMOD; ++q)
            a2 = fmaf(mh[q], mod_w2[((size_t)n * HMOD + q) * 64 + d], a2);
        gatep[n * 64 + d] = tanh_fast(a2);
    }
}

// ---------- kernel 2: per-node projections y = w1n.h, beffpb = w1h.h + b1 ----------

__global__ __launch_bounds__(512, 4) void node_kernel(
    const float* __restrict__ h, const float* __restrict__ msg_w1,
    const float* __restrict__ msg_b1,
    unsigned short* __restrict__ yws, unsigned short* __restrict__ bews)
{
    __shared__ __align__(16) unsigned short ybuf_all[8][16 * 256];  // 8KB/wave
    int tid = threadIdx.x, bid = blockIdx.x;
    int n = bid >> 1;
    int wave = tid >> 6, lane = tid & 63;
    int lrow = lane & 15, lgrp = lane >> 4;
    int c0 = (bid & 1) * 128 + wave * 16;
    unsigned short* ybuf = ybuf_all[wave];

    uint4 bf[2];
    {
        const float* hp = h + ((size_t)n * C_N + (c0 + lrow)) * 64;
        bf[0] = packf8(hp + lgrp * 8);
        bf[1] = packf8(hp + 32 + lgrp * 8);
    }
    for (int nbM = 0; nbM < 16; ++nbM) {
        int o = nbM * 16 + lrow;
        uint4 af[2];
        #pragma unroll
        for (int kf = 0; kf < 2; ++kf) {
            int k = kf * 32 + lgrp * 8;
            const float* wp = (o < 128) ? (msg_w1 + (size_t)o * 128 + k)
                                        : (msg_w1 + (size_t)(o - 128) * 128 + 64 + k);
            af[kf] = packf8(wp);
        }
        f32x4v acc = {0.f, 0.f, 0.f, 0.f};
        acc = mfma16(af[0], bf[0], acc);
        acc = mfma16(af[1], bf[1], acc);
        float4 addv = {0.f, 0.f, 0.f, 0.f};
        if (nbM >= 8) addv = *(const float4*)(msg_b1 + (nbM - 8) * 16 + lgrp * 4);
        uint2 pk = make_uint2(cvtpk(acc[0] + addv.x, acc[1] + addv.y),
                              cvtpk(acc[2] + addv.z, acc[3] + addv.w));
        int byte = lrow * 512 + ((nbM * 32 + lgrp * 8) ^ ((lrow & 7) << 4));
        *reinterpret_cast<uint2*>(reinterpret_cast<char*>(ybuf) + byte) = pk;
    }
    #pragma unroll
    for (int pass = 0; pass < 8; ++pass) {
        int idx = pass * 64 + lane;
        int row = idx >> 5, col = idx & 31;
        int byte = row * 512 + ((col * 16) ^ ((row & 7) << 4));
        uint4 v = *reinterpret_cast<const uint4*>(reinterpret_cast<const char*>(ybuf) + byte);
        size_t rb = (((size_t)n * C_N + c0 + row) * 128) * 2;
        if (col < 16)
            *reinterpret_cast<uint4*>(reinterpret_cast<char*>(yws) + rb + col * 16) = v;
        else
            *reinterpret_cast<uint4*>(reinterpret_cast<char*>(bews) + rb + (col - 16) * 16) = v;
    }
}

// ---------- kernel 3: attention weights -> packed f16 k-pairs [kp][t] ----------

__global__ __launch_bounds__(256, 4) void att_kernel(
    const float* __restrict__ neuron_id, const float* __restrict__ neuron_key,
    const int* __restrict__ conn_idx, unsigned* __restrict__ att2)
{
    int tid = threadIdx.x, bid = blockIdx.x;
    int wave = tid >> 6, lane = tid & 63;
    int lrow = lane & 15, t = lane >> 4;
    int base = bid * 64 + wave * 16;

    for (int i = 0; i < 16; ++i) {
        int gidx = base + i;
        int jv = conn_idx[(size_t)gidx * 16 + lrow];
        const float* kp = neuron_id + ((size_t)(gidx & ~255) + jv) * 64 + t * 16;
        const float* qp = neuron_key + (size_t)gidx * 64 + t * 16;
        float4 k0 = *(const float4*)kp,       k1 = *(const float4*)(kp + 4),
               k2 = *(const float4*)(kp + 8), k3 = *(const float4*)(kp + 12);
        float4 q0 = *(const float4*)qp,       q1 = *(const float4*)(qp + 4),
               q2 = *(const float4*)(qp + 8), q3 = *(const float4*)(qp + 12);
        float dt = k0.x*q0.x + k0.y*q0.y + k0.z*q0.z + k0.w*q0.w
                 + k1.x*q1.x + k1.y*q1.y + k1.z*q1.z + k1.w*q1.w
                 + k2.x*q2.x + k2.y*q2.y + k2.z*q2.z + k2.w*q2.w
                 + k3.x*q3.x + k3.y*q3.y + k3.z*q3.z + k3.w*q3.w;
        float lg = dt * 0.25f;
        float mx = lg;
        mx = fmaxf(mx, __shfl_xor(mx, 1));
        mx = fmaxf(mx, __shfl_xor(mx, 2));
        mx = fmaxf(mx, __shfl_xor(mx, 4));
        mx = fmaxf(mx, __shfl_xor(mx, 8));
        float ex = __expf(lg - mx);
        float sm = ex;
        sm += __shfl_xor(sm, 1);
        sm += __shfl_xor(sm, 2);
        sm += __shfl_xor(sm, 4);
        sm += __shfl_xor(sm, 8);
        float av = ex * __builtin_amdgcn_rcpf(sm);
        float avn = __shfl_down(av, 1);
        if ((lrow & 1) == 0) {
            att2[(size_t)gidx * 32 + (lrow >> 1) * 4 + t] =
                __builtin_bit_cast(unsigned, __builtin_amdgcn_cvt_pkrtz(av, avn));
        }
    }
}

// ---------- kernel 4: edge phase (v4: sigma-gelu + fdot2 + 2-neuron ILP) ----------
// 256 blocks (half-cell) x 1024 thr (16 waves x 8 neurons as 4 pairs).
// y-table + att f16-pairs staged in LDS; per kp: 4 ds gathers + 2 att b128 +
// 8 sgelu + 4 pkrtz + 16 fdot2 across 2 neurons. L2 mfma per 4 neurons.

__global__ __launch_bounds__(1024, 4) void edge_kernel(
    const unsigned short* __restrict__ yws, const unsigned short* __restrict__ bews,
    const unsigned* __restrict__ att2, const int* __restrict__ conn_idx,
    const float* __restrict__ msg_w2, const float* __restrict__ msg_gs1,
    const float* __restrict__ msg_gb1, const float* __restrict__ msg_gs2,
    const float* __restrict__ msg_b2, const float* __restrict__ msg_gb2,
    const int* __restrict__ cell_to_group,
    unsigned short* __restrict__ aggws)
{
    __shared__ __align__(16) unsigned yl32[C_N * 64];                  // 64KB
    __shared__ __align__(16) unsigned attl[128 * 32];                  // 16KB
    __shared__ __align__(16) unsigned short pbuf_all[16][16 * 128];    // 64KB
    __shared__ __align__(16) unsigned short aggT_all[16][4 * 64];      // 8KB
    int tid = threadIdx.x, bid = blockIdx.x;
    int n = bid >> 1;
    int g = cell_to_group[n];
    int wave = tid >> 6, lane = tid & 63;
    int lrow = lane & 15, lgrp = lane >> 4;
    int base = n * C_N + (bid & 1) * 128 + wave * 8;

    // ---- stage y-table (64KB) and att pairs (16KB) ----
    {
        const uint4* src = (const uint4*)((const char*)yws + (size_t)n * C_N * 256);
        uint4* dst = (uint4*)yl32;
        #pragma unroll
        for (int it = 0; it < 4; ++it) dst[it * 1024 + tid] = src[it * 1024 + tid];
        const uint4* asrc = (const uint4*)(att2 + ((size_t)n * 256 + (bid & 1) * 128) * 32);
        ((uint4*)attl)[tid] = asrc[tid];
    }

    uint4 w2f[4][4];
    float mb2c[4];
    load_w2_folded(msg_w2, msg_gs1, msg_gb1, msg_gs2, msg_b2, msg_gb2,
                   g, lrow, lgrp, w2f, mb2c);
    __syncthreads();

    char* pbuf_b = reinterpret_cast<char*>(pbuf_all[wave]);
    char* aggT_b = reinterpret_cast<char*>(aggT_all[wave]);
    const unsigned* bews32 = (const unsigned*)bews;

    // prefetch pair 0
    int jvA = conn_idx[(size_t)base * 16 + lrow];
    int jvB = conn_idx[(size_t)(base + 1) * 16 + lrow];
    unsigned bepA = bews32[(size_t)base * 64 + lane];
    unsigned bepB = bews32[(size_t)(base + 1) * 64 + lane];

    #pragma unroll
    for (int batch = 0; batch < 2; ++batch) {
        #pragma unroll
        for (int pb = 0; pb < 2; ++pb) {
            int pr = batch * 2 + pb;
            int npr = (pr < 3) ? (pr + 1) : 3;
            int gA_n = base + npr * 2;
            int jvA_n = conn_idx[(size_t)gA_n * 16 + lrow];
            int jvB_n = conn_idx[(size_t)(gA_n + 1) * 16 + lrow];
            unsigned bepA_n = bews32[(size_t)gA_n * 64 + lane];
            unsigned bepB_n = bews32[(size_t)(gA_n + 1) * 64 + lane];

            float beA0 = bflo(bepA), beA1 = bfhi(bepA);
            float beB0 = bflo(bepB), beB1 = bfhi(bepB);
            int laA = wave * 8 + pr * 2, laB = laA + 1;
            float pA[4][2] = {{0.f,0.f},{0.f,0.f},{0.f,0.f},{0.f,0.f}};
            float pB[4][2] = {{0.f,0.f},{0.f,0.f},{0.f,0.f},{0.f,0.f}};

            #pragma unroll
            for (int kp = 0; kp < 8; ++kp) {
                int jA0 = __builtin_amdgcn_readlane(jvA, 2 * kp);
                int jA1 = __builtin_amdgcn_readlane(jvA, 2 * kp + 1);
                int jB0 = __builtin_amdgcn_readlane(jvB, 2 * kp);
                int jB1 = __builtin_amdgcn_readlane(jvB, 2 * kp + 1);
                unsigned uyA0 = yl32[jA0 * 64 + lane];
                unsigned uyA1 = yl32[jA1 * 64 + lane];
                unsigned uyB0 = yl32[jB0 * 64 + lane];
                unsigned uyB1 = yl32[jB1 * 64 + lane];
                uint4 aqA = *reinterpret_cast<const uint4*>(&attl[laA * 32 + kp * 4]);
                uint4 aqB = *reinterpret_cast<const uint4*>(&attl[laB * 32 + kp * 4]);

                float gA00 = sgelu(bflo(uyA0) + beA0), gA01 = sgelu(bfhi(uyA0) + beA1);
                float gA10 = sgelu(bflo(uyA1) + beA0), gA11 = sgelu(bfhi(uyA1) + beA1);
                float gB00 = sgelu(bflo(uyB0) + beB0), gB01 = sgelu(bfhi(uyB0) + beB1);
                float gB10 = sgelu(bflo(uyB1) + beB0), gB11 = sgelu(bfhi(uyB1) + beB1);
                half2_t GA0 = pkrtz(gA00, gA10);
                half2_t GA1 = pkrtz(gA01, gA11);
                half2_t GB0 = pkrtz(gB00, gB10);
                half2_t GB1 = pkrtz(gB01, gB11);

                const unsigned* aA = &aqA.x;
                const unsigned* aB = &aqB.x;
                #pragma unroll
                for (int t = 0; t < 4; ++t) {
                    half2_t hA = __builtin_bit_cast(half2_t, aA[t]);
                    half2_t hB = __builtin_bit_cast(half2_t, aB[t]);
                    pA[t][0] = __builtin_amdgcn_fdot2(GA0, hA, pA[t][0], false);
                    pA[t][1] = __builtin_amdgcn_fdot2(GA1, hA, pA[t][1], false);
                    pB[t][0] = __builtin_amdgcn_fdot2(GB0, hB, pB[t][0], false);
                    pB[t][1] = __builtin_amdgcn_fdot2(GB1, hB, pB[t][1], false);
                }
            }
            // write pbuf rows ci = pb*2 (A), pb*2+1 (B)
            #pragma unroll
            for (int t = 0; t < 4; ++t) {
                int rowA = t * 4 + pb * 2, rowB = rowA + 1;
                unsigned pkA = cvtpk(pA[t][0], pA[t][1]);
                unsigned pkB = cvtpk(pB[t][0], pB[t][1]);
                *reinterpret_cast<unsigned*>(
                    pbuf_b + rowA * 256 + ((lane * 4) ^ ((rowA & 7) << 4))) = pkA;
                *reinterpret_cast<unsigned*>(
                    pbuf_b + rowB * 256 + ((lane * 4) ^ ((rowB & 7) << 4))) = pkB;
            }
            jvA = jvA_n; jvB = jvB_n; bepA = bepA_n; bepB = bepB_n;
        }
        // ---- L2: per head t, A rows = 4 neurons (dup x4), B = folded w2 ----
        #pragma unroll
        for (int t = 0; t < 4; ++t) {
            f32x4v acc = {0.f, 0.f, 0.f, 0.f};
            #pragma unroll
            for (int kf = 0; kf < 4; ++kf) {
                int row = t * 4 + (lrow & 3);
                uint4 a = *reinterpret_cast<const uint4*>(
                    pbuf_b + row * 256 + ((kf * 64 + lgrp * 16) ^ ((row & 7) << 4)));
                acc = mfma16(a, w2f[t][kf], acc);
            }
            if (lgrp == 0) {
                #pragma unroll
                for (int r = 0; r < 4; ++r) {
                    float v = acc[r] + mb2c[t];
                    int byte = r * 128 + ((((t * 16 + lrow)) * 2) ^ ((r & 7) << 4));
                    *reinterpret_cast<unsigned short*>(aggT_b + byte) = f2bf(v);
                }
            }
        }
        if (lane < 32) {
            int row = lane >> 3, col = lane & 7;
            int byte = row * 128 + ((col * 16) ^ ((row & 7) << 4));
            uint4 v = *reinterpret_cast<const uint4*>(aggT_b + byte);
            *reinterpret_cast<uint4*>(
                (char*)aggws + (size_t)(base + batch * 4 + row) * 128 + col * 16) = v;
        }
    }
}

// ---------- kernel 5: state MLP + residual ----------

__global__ __launch_bounds__(512, 4) void state_kernel(
    const float* __restrict__ h, const unsigned short* __restrict__ aggws,
    const float* __restrict__ gatep,
    const float* __restrict__ state_w1, const float* __restrict__ state_b1,
    const float* __restrict__ state_gs1, const float* __restrict__ state_gb1,
    const float* __restrict__ state_w2, const float* __restrict__ state_b2,
    const float* __restrict__ state_gs2, const float* __restrict__ state_gb2,
    const int* __restrict__ cell_to_group, float* __restrict__ out)
{
    __shared__ __align__(16) unsigned short w1s[128 * 128];      // 32KB
    __shared__ __align__(16) unsigned short s1b_all[8][16 * 128]; // 4KB/wave
    int tid = threadIdx.x, bid = blockIdx.x;
    int n = bid >> 1;
    int g = cell_to_group[n];

    for (int idx = tid; idx < 2048; idx += 512) {
        int row = idx >> 4, ch = idx & 15;
        uint4 p = packf8(state_w1 + (size_t)row * 128 + ch * 8);
        int byte = row * 256 + ((ch * 16) ^ ((row & 7) << 4));
        *reinterpret_cast<uint4*>(reinterpret_cast<char*>(w1s) + byte) = p;
    }
    __syncthreads();

    int wave = tid >> 6, lane = tid & 63;
    int lrow = lane & 15, lgrp = lane >> 4;
    int c0 = (bid & 1) * 128 + wave * 16;
    unsigned short* s1b = s1b_all[wave];

    uint4 sB[4];
    {
        const float* hp = h + ((size_t)n * C_N + c0 + lrow) * 64;
        sB[0] = packf8(hp + lgrp * 8);
        sB[1] = packf8(hp + 32 + lgrp * 8);
        const char* ap = (const char*)aggws + ((size_t)n * C_N + c0 + lrow) * 128;
        sB[2] = *reinterpret_cast<const uint4*>(ap + lgrp * 16);
        sB[3] = *reinterpret_cast<const uint4*>(ap + 64 + lgrp * 16);
    }
    for (int nbM = 0; nbM < 8; ++nbM) {
        uint4 wA[4];
        #pragma unroll
        for (int kf = 0; kf < 4; ++kf)
            wA[kf] = *reinterpret_cast<const uint4*>(
                reinterpret_cast<const char*>(w1s) +
                (nbM * 16 + lrow) * 256 + ((kf * 64 + lgrp * 16) ^ ((lrow & 7) << 4)));
        f32x4v acc = {0.f, 0.f, 0.f, 0.f};
        #pragma unroll
        for (int kf = 0; kf < 4; ++kf) acc = mfma16(wA[kf], sB[kf], acc);
        float4 b1q = *(const float4*)(state_b1 + nbM * 16 + lgrp * 4);
        float g0 = gelu_f(acc[0] + b1q.x), g1 = gelu_f(acc[1] + b1q.y);
        float g2 = gelu_f(acc[2] + b1q.z), g3 = gelu_f(acc[3] + b1q.w);
        uint2 pk = make_uint2(cvtpk(g0, g1), cvtpk(g2, g3));
        int byte = lrow * 256 + ((nbM * 32 + lgrp * 8) ^ ((lrow & 7) << 4));
        *reinterpret_cast<uint2*>(reinterpret_cast<char*>(s1b) + byte) = pk;
    }

    uint4 w2sf[4][4];
    float sb2c[4];
    load_w2_folded(state_w2, state_gs1, state_gb1, state_gs2, state_b2, state_gb2,
                   g, lrow, lgrp, w2sf, sb2c);
    uint4 s1A[4];
    #pragma unroll
    for (int kf = 0; kf < 4; ++kf)
        s1A[kf] = *reinterpret_cast<const uint4*>(
            reinterpret_cast<const char*>(s1b) +
            lrow * 256 + ((kf * 64 + lgrp * 16) ^ ((lrow & 7) << 4)));

    float* dT = reinterpret_cast<float*>(s1b);   // reuse 4KB as [16c][64d] f32
    #pragma unroll
    for (int nb2 = 0; nb2 < 4; ++nb2) {
        f32x4v acc = {0.f, 0.f, 0.f, 0.f};
        #pragma unroll
        for (int kf = 0; kf < 4; ++kf) acc = mfma16(s1A[kf], w2sf[nb2][kf], acc);
        #pragma unroll
        for (int r = 0; r < 4; ++r) {
            int c = lgrp * 4 + r;
            int d = nb2 * 16 + lrow;
            int byte = c * 256 + ((d * 4) ^ ((c & 7) << 4));
            *reinterpret_cast<float*>(reinterpret_cast<char*>(dT) + byte) = acc[r] + sb2c[nb2];
        }
    }
    #pragma unroll
    for (int pass = 0; pass < 4; ++pass) {
        int idx = pass * 64 + lane;
        int row = idx >> 4, col = idx & 15;
        int byte = row * 256 + ((col * 16) ^ ((row & 7) << 4));
        float4 dv = *reinterpret_cast<const float4*>(reinterpret_cast<const char*>(dT) + byte);
        size_t off = ((size_t)n * C_N + c0 + row) * 64 + col * 4;
        float4 hv = *(const float4*)(h + off);
        float4 gv = *(const float4*)(gatep + n * 64 + col * 4);
        float4 o;
        o.x = fmaf(gv.x, dv.x, hv.x);
        o.y = fmaf(gv.y, dv.y, hv.y);
        o.z = fmaf(gv.z, dv.z, hv.z);
        o.w = fmaf(gv.w, dv.w, hv.w);
        *(float4*)(out + off) = o;
    }
}

// ---------- launch ----------

extern "C" void kernel_launch(void* const* d_in, const int* in_sizes, int n_in,
                              void* d_out, int out_size, void* d_ws, size_t ws_size,
                              hipStream_t stream) {
    (void)in_sizes; (void)n_in; (void)out_size; (void)ws_size;
    const float* h          = (const float*)d_in[0];
    const float* neuron_id  = (const float*)d_in[1];
    const float* neuron_key = (const float*)d_in[2];
    const float* state_w1   = (const float*)d_in[3];
    const float* state_b1   = (const float*)d_in[4];
    const float* state_gs1  = (const float*)d_in[5];
    const float* state_gb1  = (const float*)d_in[6];
    const float* state_w2   = (const float*)d_in[7];
    const float* state_b2   = (const float*)d_in[8];
    const float* state_gs2  = (const float*)d_in[9];
    const float* state_gb2  = (const float*)d_in[10];
    const float* msg_w1     = (const float*)d_in[11];
    const float* msg_b1     = (const float*)d_in[12];
    const float* msg_gs1    = (const float*)d_in[13];
    const float* msg_gb1    = (const float*)d_in[14];
    const float* msg_w2     = (const float*)d_in[15];
    const float* msg_b2     = (const float*)d_in[16];
    const float* msg_gs2    = (const float*)d_in[17];
    const float* msg_gb2    = (const float*)d_in[18];
    const float* mod_w1     = (const float*)d_in[19];
    const float* mod_b1     = (const float*)d_in[20];
    const float* mod_w2     = (const float*)d_in[21];
    const float* mod_b2     = (const float*)d_in[22];
    const int*   conn_idx   = (const int*)d_in[23];
    const int*   c2g        = (const int*)d_in[24];

    char* ws = (char*)d_ws;
    float*          gatep = (float*)ws;                                        // 32 KB
    unsigned short* yws   = (unsigned short*)(ws + (32u << 10));               // 8 MB
    unsigned short* bews  = (unsigned short*)(ws + (32u << 10) + (8u << 20));  // 8 MB
    unsigned*       att2  = (unsigned*)(ws + (32u << 10) + (16u << 20));       // 4 MB
    unsigned short* aggws = (unsigned short*)(ws + (32u << 10) + (24u << 20)); // 4 MB
    float* outp = (float*)d_out;

    gate_kernel<<<dim3(N_CELLS), dim3(1024), 0, stream>>>(
        h, mod_w1, mod_b1, mod_w2, mod_b2, gatep);
    node_kernel<<<dim3(256), dim3(512), 0, stream>>>(
        h, msg_w1, msg_b1, yws, bews);
    att_kernel<<<dim3(512), dim3(256), 0, stream>>>(
        neuron_id, neuron_key, conn_idx, att2);
    edge_kernel<<<dim3(256), dim3(1024), 0, stream>>>(
        yws, bews, att2, conn_idx,
        msg_w2, msg_gs1, msg_gb1, msg_gs2, msg_b2, msg_gb2, c2g, aggws);
    state_kernel<<<dim3(256), dim3(512), 0, stream>>>(
        h, aggws, gatep,
        state_w1, state_b1, state_gs1, state_gb1,
        state_w2, state_b2, state_gs2, state_gb2, c2g, outp);
}

// Round 8
// 116.223 us; speedup vs baseline: 1.1719x; 1.1719x over previous
//
#include <hip/hip_runtime.h>
#include <hip/hip_bf16.h>

#define N_CELLS 128
#define C_N     256
#define K_NB    16
#define D_N     64
#define G_N     8
#define HS      128
#define HM      128
#define HMOD    64

typedef __bf16 bf16x8 __attribute__((ext_vector_type(8)));
typedef float  f32x4v __attribute__((ext_vector_type(4)));
typedef _Float16 half2_t __attribute__((ext_vector_type(2)));

// ---------- helpers ----------

__device__ __forceinline__ unsigned cvtpk(float lo, float hi) {
    __hip_bfloat162 t = __float22bfloat162_rn(float2{lo, hi});
    return *reinterpret_cast<unsigned*>(&t);
}

__device__ __forceinline__ unsigned short f2bf(float f) {
    return (unsigned short)(cvtpk(f, 0.f) & 0xffffu);
}

__device__ __forceinline__ float bflo(unsigned u) { return __uint_as_float(u << 16); }
__device__ __forceinline__ float bfhi(unsigned u) { return __uint_as_float(u & 0xffff0000u); }

__device__ __forceinline__ half2_t pkrtz(float lo, float hi) {
    return __builtin_bit_cast(half2_t, __builtin_amdgcn_cvt_pkrtz(lo, hi));
}

__device__ __forceinline__ half2_t h2(unsigned u) {
    return __builtin_bit_cast(half2_t, u);
}

__device__ __forceinline__ f32x4v mfma16(uint4 a, uint4 b, f32x4v c) {
    return __builtin_amdgcn_mfma_f32_16x16x32_bf16(
        __builtin_bit_cast(bf16x8, a), __builtin_bit_cast(bf16x8, b), c, 0, 0, 0);
}

__device__ __forceinline__ float gelu_f(float x) {      // exact tanh-gelu (node/state)
    float x2 = x * x;
    float u  = x * fmaf(x2, 0.044715f, 1.0f);
    float e  = __expf(1.5957691216057308f * u);
    float r  = __builtin_amdgcn_rcpf(e + 1.0f);
    return x - x * r;
}

__device__ __forceinline__ float sgelu(float x) {       // sigmoid-gelu (edge)
    float e = __expf(-1.702f * x);
    float r = __builtin_amdgcn_rcpf(e + 1.0f);
    return x * r;
}

__device__ __forceinline__ float tanh_fast(float z) {
    float e = __expf(2.0f * z);
    return 1.0f - 2.0f / (e + 1.0f);
}

__device__ __forceinline__ uint4 packf8(const float* p) {
    float4 a = *(const float4*)p, b = *(const float4*)(p + 4);
    return make_uint4(cvtpk(a.x, a.y), cvtpk(a.z, a.w), cvtpk(b.x, b.y), cvtpk(b.z, b.w));
}

// wf = gs2[d] * w2[d][k] * gs1[k];  c2 = gs2*(w2.gb1 + b2) + gb2   (verified R2)
__device__ __forceinline__ void load_w2_folded(
    const float* __restrict__ w2, const float* __restrict__ gs1,
    const float* __restrict__ gb1, const float* __restrict__ gs2,
    const float* __restrict__ b2, const float* __restrict__ gb2,
    int g, int lrow, int lgrp, uint4 wf[4][4], float c2[4])
{
    #pragma unroll
    for (int nb2 = 0; nb2 < 4; ++nb2) {
        int d = nb2 * 16 + lrow;
        float gs2d = gs2[g * 64 + d];
        float cgb = 0.0f;
        #pragma unroll
        for (int kf = 0; kf < 4; ++kf) {
            int k0 = kf * 32 + lgrp * 8;
            const float* wp = w2 + d * 128 + k0;
            float4 wa = *(const float4*)wp, wb = *(const float4*)(wp + 4);
            const float* gp = gs1 + g * 128 + k0;
            float4 ga = *(const float4*)gp, gbv = *(const float4*)(gp + 4);
            const float* bp = gb1 + g * 128 + k0;
            float4 ba = *(const float4*)bp, bbv = *(const float4*)(bp + 4);
            cgb += wa.x*ba.x + wa.y*ba.y + wa.z*ba.z + wa.w*ba.w
                 + wb.x*bbv.x + wb.y*bbv.y + wb.z*bbv.z + wb.w*bbv.w;
            wf[nb2][kf] = make_uint4(
                cvtpk(wa.x*ga.x*gs2d,  wa.y*ga.y*gs2d),
                cvtpk(wa.z*ga.z*gs2d,  wa.w*ga.w*gs2d),
                cvtpk(wb.x*gbv.x*gs2d, wb.y*gbv.y*gs2d),
                cvtpk(wb.z*gbv.z*gs2d, wb.w*gbv.w*gs2d));
        }
        cgb += __shfl_xor(cgb, 16);
        cgb += __shfl_xor(cgb, 32);
        c2[nb2] = fmaf(gs2d, cgb + b2[d], gb2[g * 64 + d]);
    }
}

// ---------- kernel 1: per-cell modulation gate ----------

__global__ __launch_bounds__(1024) void gate_kernel(
    const float* __restrict__ h,
    const float* __restrict__ mod_w1, const float* __restrict__ mod_b1,
    const float* __restrict__ mod_w2, const float* __restrict__ mod_b2,
    float* __restrict__ gatep)
{
    __shared__ float red[16][64];
    __shared__ float pooled[64];
    __shared__ float mh[64];
    int n = blockIdx.x, tid = threadIdx.x;
    int d = tid & 63, part = tid >> 6;
    const float* hn = h + (size_t)n * C_N * 64;
    float acc = 0.0f;
    #pragma unroll 4
    for (int i = 0; i < 16; ++i) acc += hn[(part * 16 + i) * 64 + d];
    red[part][d] = acc;
    __syncthreads();
    if (tid < 64) {
        float s = 0.0f;
        #pragma unroll
        for (int p = 0; p < 16; ++p) s += red[p][d];
        pooled[d] = s * (1.0f / 256.0f);
    }
    __syncthreads();
    if (tid < 64) {
        float a1 = mod_b1[n * HMOD + d];
        for (int q = 0; q < 64; ++q)
            a1 = fmaf(pooled[q], mod_w1[((size_t)n * 64 + q) * HMOD + d], a1);
        mh[d] = tanh_fast(a1);
    }
    __syncthreads();
    if (tid < 64) {
        float a2 = mod_b2[n * 64 + d];
        for (int q = 0; q < HMOD; ++q)
            a2 = fmaf(mh[q], mod_w2[((size_t)n * HMOD + q) * 64 + d], a2);
        gatep[n * 64 + d] = tanh_fast(a2);
    }
}

// ---------- kernel 2: per-node projections y = w1n.h, beffpb = w1h.h + b1 ----------

__global__ __launch_bounds__(512, 4) void node_kernel(
    const float* __restrict__ h, const float* __restrict__ msg_w1,
    const float* __restrict__ msg_b1,
    unsigned short* __restrict__ yws, unsigned short* __restrict__ bews)
{
    __shared__ __align__(16) unsigned short ybuf_all[8][16 * 256];  // 8KB/wave
    int tid = threadIdx.x, bid = blockIdx.x;
    int n = bid >> 1;
    int wave = tid >> 6, lane = tid & 63;
    int lrow = lane & 15, lgrp = lane >> 4;
    int c0 = (bid & 1) * 128 + wave * 16;
    unsigned short* ybuf = ybuf_all[wave];

    uint4 bf[2];
    {
        const float* hp = h + ((size_t)n * C_N + (c0 + lrow)) * 64;
        bf[0] = packf8(hp + lgrp * 8);
        bf[1] = packf8(hp + 32 + lgrp * 8);
    }
    for (int nbM = 0; nbM < 16; ++nbM) {
        int o = nbM * 16 + lrow;
        uint4 af[2];
        #pragma unroll
        for (int kf = 0; kf < 2; ++kf) {
            int k = kf * 32 + lgrp * 8;
            const float* wp = (o < 128) ? (msg_w1 + (size_t)o * 128 + k)
                                        : (msg_w1 + (size_t)(o - 128) * 128 + 64 + k);
            af[kf] = packf8(wp);
        }
        f32x4v acc = {0.f, 0.f, 0.f, 0.f};
        acc = mfma16(af[0], bf[0], acc);
        acc = mfma16(af[1], bf[1], acc);
        float4 addv = {0.f, 0.f, 0.f, 0.f};
        if (nbM >= 8) addv = *(const float4*)(msg_b1 + (nbM - 8) * 16 + lgrp * 4);
        uint2 pk = make_uint2(cvtpk(acc[0] + addv.x, acc[1] + addv.y),
                              cvtpk(acc[2] + addv.z, acc[3] + addv.w));
        int byte = lrow * 512 + ((nbM * 32 + lgrp * 8) ^ ((lrow & 7) << 4));
        *reinterpret_cast<uint2*>(reinterpret_cast<char*>(ybuf) + byte) = pk;
    }
    #pragma unroll
    for (int pass = 0; pass < 8; ++pass) {
        int idx = pass * 64 + lane;
        int row = idx >> 5, col = idx & 31;
        int byte = row * 512 + ((col * 16) ^ ((row & 7) << 4));
        uint4 v = *reinterpret_cast<const uint4*>(reinterpret_cast<const char*>(ybuf) + byte);
        size_t rb = (((size_t)n * C_N + c0 + row) * 128) * 2;
        if (col < 16)
            *reinterpret_cast<uint4*>(reinterpret_cast<char*>(yws) + rb + col * 16) = v;
        else
            *reinterpret_cast<uint4*>(reinterpret_cast<char*>(bews) + rb + (col - 16) * 16) = v;
    }
}

// ---------- kernel 3: attention weights -> packed f16 k-pairs [kp][t] ----------

__global__ __launch_bounds__(256, 4) void att_kernel(
    const float* __restrict__ neuron_id, const float* __restrict__ neuron_key,
    const int* __restrict__ conn_idx, unsigned* __restrict__ att2)
{
    int tid = threadIdx.x, bid = blockIdx.x;
    int wave = tid >> 6, lane = tid & 63;
    int lrow = lane & 15, t = lane >> 4;
    int base = bid * 64 + wave * 16;

    for (int i = 0; i < 16; ++i) {
        int gidx = base + i;
        int jv = conn_idx[(size_t)gidx * 16 + lrow];
        const float* kp = neuron_id + ((size_t)(gidx & ~255) + jv) * 64 + t * 16;
        const float* qp = neuron_key + (size_t)gidx * 64 + t * 16;
        float4 k0 = *(const float4*)kp,       k1 = *(const float4*)(kp + 4),
               k2 = *(const float4*)(kp + 8), k3 = *(const float4*)(kp + 12);
        float4 q0 = *(const float4*)qp,       q1 = *(const float4*)(qp + 4),
               q2 = *(const float4*)(qp + 8), q3 = *(const float4*)(qp + 12);
        float dt = k0.x*q0.x + k0.y*q0.y + k0.z*q0.z + k0.w*q0.w
                 + k1.x*q1.x + k1.y*q1.y + k1.z*q1.z + k1.w*q1.w
                 + k2.x*q2.x + k2.y*q2.y + k2.z*q2.z + k2.w*q2.w
                 + k3.x*q3.x + k3.y*q3.y + k3.z*q3.z + k3.w*q3.w;
        float lg = dt * 0.25f;
        float mx = lg;
        mx = fmaxf(mx, __shfl_xor(mx, 1));
        mx = fmaxf(mx, __shfl_xor(mx, 2));
        mx = fmaxf(mx, __shfl_xor(mx, 4));
        mx = fmaxf(mx, __shfl_xor(mx, 8));
        float ex = __expf(lg - mx);
        float sm = ex;
        sm += __shfl_xor(sm, 1);
        sm += __shfl_xor(sm, 2);
        sm += __shfl_xor(sm, 4);
        sm += __shfl_xor(sm, 8);
        float av = ex * __builtin_amdgcn_rcpf(sm);
        float avn = __shfl_down(av, 1);
        if ((lrow & 1) == 0) {
            att2[(size_t)gidx * 32 + (lrow >> 1) * 4 + t] =
                __builtin_bit_cast(unsigned, __builtin_amdgcn_cvt_pkrtz(av, avn));
        }
    }
}

// ---------- kernel 4: edge phase (v5: no scratch — w2 in LDS, explicit components) ----------
// 256 blocks (half-cell) x 1024 thr (16 waves x 8 neurons as 4 pairs).
// y-table (64K) + att f16 (16K) + folded w2 frags (16K) in LDS; per pair:
// kp loop (4 ds gathers + 2 att b128 + 8 sgelu + 4 pkrtz + 16 fdot2) -> pbuf
// (2KB/wave) -> L2 mfma (B-frags from LDS) -> aggT (256B/wave) -> aggws.

__global__ __launch_bounds__(1024, 4) void edge_kernel(
    const unsigned short* __restrict__ yws, const unsigned short* __restrict__ bews,
    const unsigned* __restrict__ att2, const int* __restrict__ conn_idx,
    const float* __restrict__ msg_w2, const float* __restrict__ msg_gs1,
    const float* __restrict__ msg_gb1, const float* __restrict__ msg_gs2,
    const float* __restrict__ msg_b2, const float* __restrict__ msg_gb2,
    const int* __restrict__ cell_to_group,
    unsigned short* __restrict__ aggws)
{
    __shared__ __align__(16) unsigned yl32[C_N * 64];                  // 64KB
    __shared__ __align__(16) unsigned attl[128 * 32];                  // 16KB
    __shared__ __align__(16) uint4 w2l[16 * 64];                       // 16KB
    __shared__ float mb2cl[64];                                        // 256B
    __shared__ __align__(16) unsigned short pbuf_all[16][8 * 128];     // 32KB
    __shared__ __align__(16) unsigned short aggT_all[16][2 * 64];      // 4KB
    int tid = threadIdx.x, bid = blockIdx.x;
    int n = bid >> 1;
    int wave = tid >> 6, lane = tid & 63;
    int lrow = lane & 15, lgrp = lane >> 4;
    int base = n * C_N + (bid & 1) * 128 + wave * 8;

    // ---- stage y-table (64KB) and att pairs (16KB) ----
    {
        const uint4* src = (const uint4*)((const char*)yws + (size_t)n * C_N * 256);
        uint4* dst = (uint4*)yl32;
        #pragma unroll
        for (int it = 0; it < 4; ++it) dst[it * 1024 + tid] = src[it * 1024 + tid];
        const uint4* asrc = (const uint4*)(att2 + ((size_t)n * 256 + (bid & 1) * 128) * 32);
        ((uint4*)attl)[tid] = asrc[tid];
    }
    // ---- wave 0: fold w2 + constants into LDS (block-uniform) ----
    if (wave == 0) {
        uint4 w2f[4][4];
        float mb2c[4];
        int g = cell_to_group[n];
        load_w2_folded(msg_w2, msg_gs1, msg_gb1, msg_gs2, msg_b2, msg_gb2,
                       g, lrow, lgrp, w2f, mb2c);
        #pragma unroll
        for (int t = 0; t < 4; ++t) {
            #pragma unroll
            for (int kf = 0; kf < 4; ++kf)
                w2l[(t * 4 + kf) * 64 + lane] = w2f[t][kf];
            if (lgrp == 0) mb2cl[t * 16 + lrow] = mb2c[t];
        }
    }
    __syncthreads();

    float mb2r0 = mb2cl[lrow], mb2r1 = mb2cl[16 + lrow],
          mb2r2 = mb2cl[32 + lrow], mb2r3 = mb2cl[48 + lrow];
    char* pbuf_b = reinterpret_cast<char*>(pbuf_all[wave]);
    char* aggT_b = reinterpret_cast<char*>(aggT_all[wave]);
    const unsigned* bews32 = (const unsigned*)bews;

    #pragma unroll 1
    for (int pr = 0; pr < 4; ++pr) {
        int gA = base + pr * 2, gB = gA + 1;
        int jvA = conn_idx[(size_t)gA * 16 + lrow];
        int jvB = conn_idx[(size_t)gB * 16 + lrow];
        unsigned bepA = bews32[(size_t)gA * 64 + lane];
        unsigned bepB = bews32[(size_t)gB * 64 + lane];
        float beA0 = bflo(bepA), beA1 = bfhi(bepA);
        float beB0 = bflo(bepB), beB1 = bfhi(bepB);
        int laA = wave * 8 + pr * 2, laB = laA + 1;

        float pA[4][2] = {{0.f,0.f},{0.f,0.f},{0.f,0.f},{0.f,0.f}};
        float pB[4][2] = {{0.f,0.f},{0.f,0.f},{0.f,0.f},{0.f,0.f}};

        #pragma unroll
        for (int kp = 0; kp < 8; ++kp) {
            int jA0 = __builtin_amdgcn_readlane(jvA, 2 * kp);
            int jA1 = __builtin_amdgcn_readlane(jvA, 2 * kp + 1);
            int jB0 = __builtin_amdgcn_readlane(jvB, 2 * kp);
            int jB1 = __builtin_amdgcn_readlane(jvB, 2 * kp + 1);
            unsigned uyA0 = yl32[jA0 * 64 + lane];
            unsigned uyA1 = yl32[jA1 * 64 + lane];
            unsigned uyB0 = yl32[jB0 * 64 + lane];
            unsigned uyB1 = yl32[jB1 * 64 + lane];
            uint4 aqA = *reinterpret_cast<const uint4*>(&attl[laA * 32 + kp * 4]);
            uint4 aqB = *reinterpret_cast<const uint4*>(&attl[laB * 32 + kp * 4]);

            float gA00 = sgelu(bflo(uyA0) + beA0), gA01 = sgelu(bfhi(uyA0) + beA1);
            float gA10 = sgelu(bflo(uyA1) + beA0), gA11 = sgelu(bfhi(uyA1) + beA1);
            float gB00 = sgelu(bflo(uyB0) + beB0), gB01 = sgelu(bfhi(uyB0) + beB1);
            float gB10 = sgelu(bflo(uyB1) + beB0), gB11 = sgelu(bfhi(uyB1) + beB1);
            half2_t GA0 = pkrtz(gA00, gA10);
            half2_t GA1 = pkrtz(gA01, gA11);
            half2_t GB0 = pkrtz(gB00, gB10);
            half2_t GB1 = pkrtz(gB01, gB11);

            half2_t hA, hB;
            hA = h2(aqA.x); hB = h2(aqB.x);
            pA[0][0] = __builtin_amdgcn_fdot2(GA0, hA, pA[0][0], false);
            pA[0][1] = __builtin_amdgcn_fdot2(GA1, hA, pA[0][1], false);
            pB[0][0] = __builtin_amdgcn_fdot2(GB0, hB, pB[0][0], false);
            pB[0][1] = __builtin_amdgcn_fdot2(GB1, hB, pB[0][1], false);
            hA = h2(aqA.y); hB = h2(aqB.y);
            pA[1][0] = __builtin_amdgcn_fdot2(GA0, hA, pA[1][0], false);
            pA[1][1] = __builtin_amdgcn_fdot2(GA1, hA, pA[1][1], false);
            pB[1][0] = __builtin_amdgcn_fdot2(GB0, hB, pB[1][0], false);
            pB[1][1] = __builtin_amdgcn_fdot2(GB1, hB, pB[1][1], false);
            hA = h2(aqA.z); hB = h2(aqB.z);
            pA[2][0] = __builtin_amdgcn_fdot2(GA0, hA, pA[2][0], false);
            pA[2][1] = __builtin_amdgcn_fdot2(GA1, hA, pA[2][1], false);
            pB[2][0] = __builtin_amdgcn_fdot2(GB0, hB, pB[2][0], false);
            pB[2][1] = __builtin_amdgcn_fdot2(GB1, hB, pB[2][1], false);
            hA = h2(aqA.w); hB = h2(aqB.w);
            pA[3][0] = __builtin_amdgcn_fdot2(GA0, hA, pA[3][0], false);
            pA[3][1] = __builtin_amdgcn_fdot2(GA1, hA, pA[3][1], false);
            pB[3][0] = __builtin_amdgcn_fdot2(GB0, hB, pB[3][0], false);
            pB[3][1] = __builtin_amdgcn_fdot2(GB1, hB, pB[3][1], false);
        }

        // pbuf rows: t*2 (A), t*2+1 (B); 8 rows x 256B
        #pragma unroll
        for (int t = 0; t < 4; ++t) {
            int rowA = t * 2, rowB = rowA + 1;
            *reinterpret_cast<unsigned*>(
                pbuf_b + rowA * 256 + ((lane * 4) ^ ((rowA & 7) << 4))) =
                cvtpk(pA[t][0], pA[t][1]);
            *reinterpret_cast<unsigned*>(
                pbuf_b + rowB * 256 + ((lane * 4) ^ ((rowB & 7) << 4))) =
                cvtpk(pB[t][0], pB[t][1]);
        }

        // ---- L2: per head t, A rows = {A,B} dup x8, B = folded w2 from LDS ----
        #pragma unroll
        for (int t = 0; t < 4; ++t) {
            f32x4v acc = {0.f, 0.f, 0.f, 0.f};
            #pragma unroll
            for (int kf = 0; kf < 4; ++kf) {
                int row = t * 2 + (lrow & 1);
                uint4 a = *reinterpret_cast<const uint4*>(
                    pbuf_b + row * 256 + ((kf * 64 + lgrp * 16) ^ ((row & 7) << 4)));
                acc = mfma16(a, w2l[(t * 4 + kf) * 64 + lane], acc);
            }
            if (lgrp == 0) {
                float mb = (t == 0) ? mb2r0 : (t == 1) ? mb2r1 : (t == 2) ? mb2r2 : mb2r3;
                #pragma unroll
                for (int r = 0; r < 2; ++r) {
                    float v = acc[r] + mb;
                    int byte = r * 128 + ((((t * 16 + lrow)) * 2) ^ ((r & 7) << 4));
                    *reinterpret_cast<unsigned short*>(aggT_b + byte) = f2bf(v);
                }
            }
        }
        if (lane < 16) {
            int row = lane >> 3, col = lane & 7;
            int byte = row * 128 + ((col * 16) ^ ((row & 7) << 4));
            uint4 v = *reinterpret_cast<const uint4*>(aggT_b + byte);
            *reinterpret_cast<uint4*>(
                (char*)aggws + (size_t)(gA + row) * 128 + col * 16) = v;
        }
    }
}

// ---------- kernel 5: state MLP + residual ----------

__global__ __launch_bounds__(512, 4) void state_kernel(
    const float* __restrict__ h, const unsigned short* __restrict__ aggws,
    const float* __restrict__ gatep,
    const float* __restrict__ state_w1, const float* __restrict__ state_b1,
    const float* __restrict__ state_gs1, const float* __restrict__ state_gb1,
    const float* __restrict__ state_w2, const float* __restrict__ state_b2,
    const float* __restrict__ state_gs2, const float* __restrict__ state_gb2,
    const int* __restrict__ cell_to_group, float* __restrict__ out)
{
    __shared__ __align__(16) unsigned short w1s[128 * 128];      // 32KB
    __shared__ __align__(16) unsigned short s1b_all[8][16 * 128]; // 4KB/wave
    int tid = threadIdx.x, bid = blockIdx.x;
    int n = bid >> 1;
    int g = cell_to_group[n];

    for (int idx = tid; idx < 2048; idx += 512) {
        int row = idx >> 4, ch = idx & 15;
        uint4 p = packf8(state_w1 + (size_t)row * 128 + ch * 8);
        int byte = row * 256 + ((ch * 16) ^ ((row & 7) << 4));
        *reinterpret_cast<uint4*>(reinterpret_cast<char*>(w1s) + byte) = p;
    }
    __syncthreads();

    int wave = tid >> 6, lane = tid & 63;
    int lrow = lane & 15, lgrp = lane >> 4;
    int c0 = (bid & 1) * 128 + wave * 16;
    unsigned short* s1b = s1b_all[wave];

    uint4 sB[4];
    {
        const float* hp = h + ((size_t)n * C_N + c0 + lrow) * 64;
        sB[0] = packf8(hp + lgrp * 8);
        sB[1] = packf8(hp + 32 + lgrp * 8);
        const char* ap = (const char*)aggws + ((size_t)n * C_N + c0 + lrow) * 128;
        sB[2] = *reinterpret_cast<const uint4*>(ap + lgrp * 16);
        sB[3] = *reinterpret_cast<const uint4*>(ap + 64 + lgrp * 16);
    }
    for (int nbM = 0; nbM < 8; ++nbM) {
        uint4 wA[4];
        #pragma unroll
        for (int kf = 0; kf < 4; ++kf)
            wA[kf] = *reinterpret_cast<const uint4*>(
                reinterpret_cast<const char*>(w1s) +
                (nbM * 16 + lrow) * 256 + ((kf * 64 + lgrp * 16) ^ ((lrow & 7) << 4)));
        f32x4v acc = {0.f, 0.f, 0.f, 0.f};
        #pragma unroll
        for (int kf = 0; kf < 4; ++kf) acc = mfma16(wA[kf], sB[kf], acc);
        float4 b1q = *(const float4*)(state_b1 + nbM * 16 + lgrp * 4);
        float g0 = gelu_f(acc[0] + b1q.x), g1 = gelu_f(acc[1] + b1q.y);
        float g2 = gelu_f(acc[2] + b1q.z), g3 = gelu_f(acc[3] + b1q.w);
        uint2 pk = make_uint2(cvtpk(g0, g1), cvtpk(g2, g3));
        int byte = lrow * 256 + ((nbM * 32 + lgrp * 8) ^ ((lrow & 7) << 4));
        *reinterpret_cast<uint2*>(reinterpret_cast<char*>(s1b) + byte) = pk;
    }

    uint4 w2sf[4][4];
    float sb2c[4];
    load_w2_folded(state_w2, state_gs1, state_gb1, state_gs2, state_b2, state_gb2,
                   g, lrow, lgrp, w2sf, sb2c);
    uint4 s1A[4];
    #pragma unroll
    for (int kf = 0; kf < 4; ++kf)
        s1A[kf] = *reinterpret_cast<const uint4*>(
            reinterpret_cast<const char*>(s1b) +
            lrow * 256 + ((kf * 64 + lgrp * 16) ^ ((lrow & 7) << 4)));

    float* dT = reinterpret_cast<float*>(s1b);   // reuse 4KB as [16c][64d] f32
    #pragma unroll
    for (int nb2 = 0; nb2 < 4; ++nb2) {
        f32x4v acc = {0.f, 0.f, 0.f, 0.f};
        #pragma unroll
        for (int kf = 0; kf < 4; ++kf) acc = mfma16(s1A[kf], w2sf[nb2][kf], acc);
        #pragma unroll
        for (int r = 0; r < 4; ++r) {
            int c = lgrp * 4 + r;
            int d = nb2 * 16 + lrow;
            int byte = c * 256 + ((d * 4) ^ ((c & 7) << 4));
            *reinterpret_cast<float*>(reinterpret_cast<char*>(dT) + byte) = acc[r] + sb2c[nb2];
        }
    }
    #pragma unroll
    for (int pass = 0; pass < 4; ++pass) {
        int idx = pass * 64 + lane;
        int row = idx >> 4, col = idx & 15;
        int byte = row * 256 + ((col * 16) ^ ((row & 7) << 4));
        float4 dv = *reinterpret_cast<const float4*>(reinterpret_cast<const char*>(dT) + byte);
        size_t off = ((size_t)n * C_N + c0 + row) * 64 + col * 4;
        float4 hv = *(const float4*)(h + off);
        float4 gv = *(const float4*)(gatep + n * 64 + col * 4);
        float4 o;
        o.x = fmaf(gv.x, dv.x, hv.x);
        o.y = fmaf(gv.y, dv.y, hv.y);
        o.z = fmaf(gv.z, dv.z, hv.z);
        o.w = fmaf(gv.w, dv.w, hv.w);
        *(float4*)(out + off) = o;
    }
}

// ---------- launch ----------

extern "C" void kernel_launch(void* const* d_in, const int* in_sizes, int n_in,
                              void* d_out, int out_size, void* d_ws, size_t ws_size,
                              hipStream_t stream) {
    (void)in_sizes; (void)n_in; (void)out_size; (void)ws_size;
    const float* h          = (const float*)d_in[0];
    const float* neuron_id  = (const float*)d_in[1];
    const float* neuron_key = (const float*)d_in[2];
    const float* state_w1   = (const float*)d_in[3];
    const float* state_b1   = (const float*)d_in[4];
    const float* state_gs1  = (const float*)d_in[5];
    const float* state_gb1  = (const float*)d_in[6];
    const float* state_w2   = (const float*)d_in[7];
    const float* state_b2   = (const float*)d_in[8];
    const float* state_gs2  = (const float*)d_in[9];
    const float* state_gb2  = (const float*)d_in[10];
    const float* msg_w1     = (const float*)d_in[11];
    const float* msg_b1     = (const float*)d_in[12];
    const float* msg_gs1    = (const float*)d_in[13];
    const float* msg_gb1    = (const float*)d_in[14];
    const float* msg_w2     = (const float*)d_in[15];
    const float* msg_b2     = (const float*)d_in[16];
    const float* msg_gs2    = (const float*)d_in[17];
    const float* msg_gb2    = (const float*)d_in[18];
    const float* mod_w1     = (const float*)d_in[19];
    const float* mod_b1     = (const float*)d_in[20];
    const float* mod_w2     = (const float*)d_in[21];
    const float* mod_b2     = (const float*)d_in[22];
    const int*   conn_idx   = (const int*)d_in[23];
    const int*   c2g        = (const int*)d_in[24];

    char* ws = (char*)d_ws;
    float*          gatep = (float*)ws;                                        // 32 KB
    unsigned short* yws   = (unsigned short*)(ws + (32u << 10));               // 8 MB
    unsigned short* bews  = (unsigned short*)(ws + (32u << 10) + (8u << 20));  // 8 MB
    unsigned*       att2  = (unsigned*)(ws + (32u << 10) + (16u << 20));       // 4 MB
    unsigned short* aggws = (unsigned short*)(ws + (32u << 10) + (24u << 20)); // 4 MB
    float* outp = (float*)d_out;

    gate_kernel<<<dim3(N_CELLS), dim3(1024), 0, stream>>>(
        h, mod_w1, mod_b1, mod_w2, mod_b2, gatep);
    node_kernel<<<dim3(256), dim3(512), 0, stream>>>(
        h, msg_w1, msg_b1, yws, bews);
    att_kernel<<<dim3(512), dim3(256), 0, stream>>>(
        neuron_id, neuron_key, conn_idx, att2);
    edge_kernel<<<dim3(256), dim3(1024), 0, stream>>>(
        yws, bews, att2, conn_idx,
        msg_w2, msg_gs1, msg_gb1, msg_gs2, msg_b2, msg_gb2, c2g, aggws);
    state_kernel<<<dim3(256), dim3(512), 0, stream>>>(
        h, aggws, gatep,
        state_w1, state_b1, state_gs1, state_gb1,
        state_w2, state_b2, state_gs2, state_gb2, c2g, outp);
}

// Round 9
// 112.058 us; speedup vs baseline: 1.2155x; 1.0372x over previous
//
#include <hip/hip_runtime.h>
#include <hip/hip_bf16.h>

#define N_CELLS 128
#define C_N     256
#define K_NB    16
#define D_N     64
#define G_N     8
#define HS      128
#define HM      128
#define HMOD    64

typedef __bf16 bf16x8 __attribute__((ext_vector_type(8)));
typedef float  f32x4v __attribute__((ext_vector_type(4)));
typedef _Float16 half2_t __attribute__((ext_vector_type(2)));

// ---------- helpers ----------

__device__ __forceinline__ unsigned cvtpk(float lo, float hi) {
    __hip_bfloat162 t = __float22bfloat162_rn(float2{lo, hi});
    return *reinterpret_cast<unsigned*>(&t);
}

__device__ __forceinline__ unsigned short f2bf(float f) {
    return (unsigned short)(cvtpk(f, 0.f) & 0xffffu);
}

__device__ __forceinline__ float bflo(unsigned u) { return __uint_as_float(u << 16); }
__device__ __forceinline__ float bfhi(unsigned u) { return __uint_as_float(u & 0xffff0000u); }

__device__ __forceinline__ half2_t pkrtz(float lo, float hi) {
    return __builtin_bit_cast(half2_t, __builtin_amdgcn_cvt_pkrtz(lo, hi));
}

__device__ __forceinline__ half2_t h2(unsigned u) {
    return __builtin_bit_cast(half2_t, u);
}

__device__ __forceinline__ f32x4v mfma16(uint4 a, uint4 b, f32x4v c) {
    return __builtin_amdgcn_mfma_f32_16x16x32_bf16(
        __builtin_bit_cast(bf16x8, a), __builtin_bit_cast(bf16x8, b), c, 0, 0, 0);
}

__device__ __forceinline__ float gelu_f(float x) {      // exact tanh-gelu (node/state)
    float x2 = x * x;
    float u  = x * fmaf(x2, 0.044715f, 1.0f);
    float e  = __expf(1.5957691216057308f * u);
    float r  = __builtin_amdgcn_rcpf(e + 1.0f);
    return x - x * r;
}

__device__ __forceinline__ float sgelu(float x) {       // sigmoid-gelu (edge)
    float e = __expf(-1.702f * x);
    float r = __builtin_amdgcn_rcpf(e + 1.0f);
    return x * r;
}

__device__ __forceinline__ float tanh_fast(float z) {
    float e = __expf(2.0f * z);
    return 1.0f - 2.0f / (e + 1.0f);
}

__device__ __forceinline__ uint4 packf8(const float* p) {
    float4 a = *(const float4*)p, b = *(const float4*)(p + 4);
    return make_uint4(cvtpk(a.x, a.y), cvtpk(a.z, a.w), cvtpk(b.x, b.y), cvtpk(b.z, b.w));
}

// wf = gs2[d] * w2[d][k] * gs1[k];  c2 = gs2*(w2.gb1 + b2) + gb2   (verified R2)
__device__ __forceinline__ void load_w2_folded(
    const float* __restrict__ w2, const float* __restrict__ gs1,
    const float* __restrict__ gb1, const float* __restrict__ gs2,
    const float* __restrict__ b2, const float* __restrict__ gb2,
    int g, int lrow, int lgrp, uint4 wf[4][4], float c2[4])
{
    #pragma unroll
    for (int nb2 = 0; nb2 < 4; ++nb2) {
        int d = nb2 * 16 + lrow;
        float gs2d = gs2[g * 64 + d];
        float cgb = 0.0f;
        #pragma unroll
        for (int kf = 0; kf < 4; ++kf) {
            int k0 = kf * 32 + lgrp * 8;
            const float* wp = w2 + d * 128 + k0;
            float4 wa = *(const float4*)wp, wb = *(const float4*)(wp + 4);
            const float* gp = gs1 + g * 128 + k0;
            float4 ga = *(const float4*)gp, gbv = *(const float4*)(gp + 4);
            const float* bp = gb1 + g * 128 + k0;
            float4 ba = *(const float4*)bp, bbv = *(const float4*)(bp + 4);
            cgb += wa.x*ba.x + wa.y*ba.y + wa.z*ba.z + wa.w*ba.w
                 + wb.x*bbv.x + wb.y*bbv.y + wb.z*bbv.z + wb.w*bbv.w;
            wf[nb2][kf] = make_uint4(
                cvtpk(wa.x*ga.x*gs2d,  wa.y*ga.y*gs2d),
                cvtpk(wa.z*ga.z*gs2d,  wa.w*ga.w*gs2d),
                cvtpk(wb.x*gbv.x*gs2d, wb.y*gbv.y*gs2d),
                cvtpk(wb.z*gbv.z*gs2d, wb.w*gbv.w*gs2d));
        }
        cgb += __shfl_xor(cgb, 16);
        cgb += __shfl_xor(cgb, 32);
        c2[nb2] = fmaf(gs2d, cgb + b2[d], gb2[g * 64 + d]);
    }
}

// ---------- kernel 1: fused prep (node + att + gate), 640 blocks x 512 thr ----------
// blocks 0..255   : node projections  y = w1n.h -> yws, beff+b1 -> bews
// blocks 256..511 : attention -> packed f16 k-pairs att2
// blocks 512..639 : per-cell modulation gate -> gatep

__global__ __launch_bounds__(512, 2) void prep_kernel(
    const float* __restrict__ h, const float* __restrict__ neuron_id,
    const float* __restrict__ neuron_key,
    const float* __restrict__ msg_w1, const float* __restrict__ msg_b1,
    const float* __restrict__ mod_w1, const float* __restrict__ mod_b1,
    const float* __restrict__ mod_w2, const float* __restrict__ mod_b2,
    const int* __restrict__ conn_idx,
    unsigned short* __restrict__ yws, unsigned short* __restrict__ bews,
    unsigned* __restrict__ att2, float* __restrict__ gatep)
{
    __shared__ __align__(16) unsigned short shmem[8][16 * 256];   // 64KB
    int tid = threadIdx.x, bid = blockIdx.x;
    int wave = tid >> 6, lane = tid & 63;
    int lrow = lane & 15, lgrp = lane >> 4;

    if (bid < 256) {
        // ---------------- node section ----------------
        int n = bid >> 1;
        int c0 = (bid & 1) * 128 + wave * 16;
        unsigned short* ybuf = shmem[wave];

        uint4 bf[2];
        {
            const float* hp = h + ((size_t)n * C_N + (c0 + lrow)) * 64;
            bf[0] = packf8(hp + lgrp * 8);
            bf[1] = packf8(hp + 32 + lgrp * 8);
        }
        for (int nbM = 0; nbM < 16; ++nbM) {
            int o = nbM * 16 + lrow;
            uint4 af[2];
            #pragma unroll
            for (int kf = 0; kf < 2; ++kf) {
                int k = kf * 32 + lgrp * 8;
                const float* wp = (o < 128) ? (msg_w1 + (size_t)o * 128 + k)
                                            : (msg_w1 + (size_t)(o - 128) * 128 + 64 + k);
                af[kf] = packf8(wp);
            }
            f32x4v acc = {0.f, 0.f, 0.f, 0.f};
            acc = mfma16(af[0], bf[0], acc);
            acc = mfma16(af[1], bf[1], acc);
            float4 addv = {0.f, 0.f, 0.f, 0.f};
            if (nbM >= 8) addv = *(const float4*)(msg_b1 + (nbM - 8) * 16 + lgrp * 4);
            uint2 pk = make_uint2(cvtpk(acc[0] + addv.x, acc[1] + addv.y),
                                  cvtpk(acc[2] + addv.z, acc[3] + addv.w));
            int byte = lrow * 512 + ((nbM * 32 + lgrp * 8) ^ ((lrow & 7) << 4));
            *reinterpret_cast<uint2*>(reinterpret_cast<char*>(ybuf) + byte) = pk;
        }
        #pragma unroll
        for (int pass = 0; pass < 8; ++pass) {
            int idx = pass * 64 + lane;
            int row = idx >> 5, col = idx & 31;
            int byte = row * 512 + ((col * 16) ^ ((row & 7) << 4));
            uint4 v = *reinterpret_cast<const uint4*>(
                reinterpret_cast<const char*>(ybuf) + byte);
            size_t rb = (((size_t)n * C_N + c0 + row) * 128) * 2;
            if (col < 16)
                *reinterpret_cast<uint4*>(reinterpret_cast<char*>(yws) + rb + col * 16) = v;
            else
                *reinterpret_cast<uint4*>(reinterpret_cast<char*>(bews) + rb + (col - 16) * 16) = v;
        }
    } else if (bid < 512) {
        // ---------------- attention section ----------------
        int t = lgrp;
        int base = (bid - 256) * 128 + wave * 16;
        for (int i = 0; i < 16; ++i) {
            int gidx = base + i;
            int jv = conn_idx[(size_t)gidx * 16 + lrow];
            const float* kp = neuron_id + ((size_t)(gidx & ~255) + jv) * 64 + t * 16;
            const float* qp = neuron_key + (size_t)gidx * 64 + t * 16;
            float4 k0 = *(const float4*)kp,       k1 = *(const float4*)(kp + 4),
                   k2 = *(const float4*)(kp + 8), k3 = *(const float4*)(kp + 12);
            float4 q0 = *(const float4*)qp,       q1 = *(const float4*)(qp + 4),
                   q2 = *(const float4*)(qp + 8), q3 = *(const float4*)(qp + 12);
            float dt = k0.x*q0.x + k0.y*q0.y + k0.z*q0.z + k0.w*q0.w
                     + k1.x*q1.x + k1.y*q1.y + k1.z*q1.z + k1.w*q1.w
                     + k2.x*q2.x + k2.y*q2.y + k2.z*q2.z + k2.w*q2.w
                     + k3.x*q3.x + k3.y*q3.y + k3.z*q3.z + k3.w*q3.w;
            float lg = dt * 0.25f;
            float mx = lg;
            mx = fmaxf(mx, __shfl_xor(mx, 1));
            mx = fmaxf(mx, __shfl_xor(mx, 2));
            mx = fmaxf(mx, __shfl_xor(mx, 4));
            mx = fmaxf(mx, __shfl_xor(mx, 8));
            float ex = __expf(lg - mx);
            float sm = ex;
            sm += __shfl_xor(sm, 1);
            sm += __shfl_xor(sm, 2);
            sm += __shfl_xor(sm, 4);
            sm += __shfl_xor(sm, 8);
            float av = ex * __builtin_amdgcn_rcpf(sm);
            float avn = __shfl_down(av, 1);
            if ((lrow & 1) == 0) {
                att2[(size_t)gidx * 32 + (lrow >> 1) * 4 + t] =
                    __builtin_bit_cast(unsigned, __builtin_amdgcn_cvt_pkrtz(av, avn));
            }
        }
    } else {
        // ---------------- gate section ----------------
        int n = bid - 512;
        float* red   = reinterpret_cast<float*>(shmem);     // [8][64]
        float* pooled = red + 8 * 64;
        float* mh     = pooled + 64;
        int d = lane, part = wave;
        const float* hn = h + (size_t)n * C_N * 64;
        float acc = 0.0f;
        #pragma unroll 4
        for (int i = 0; i < 32; ++i) acc += hn[(part * 32 + i) * 64 + d];
        red[part * 64 + d] = acc;
        __syncthreads();
        if (tid < 64) {
            float s = 0.0f;
            #pragma unroll
            for (int p = 0; p < 8; ++p) s += red[p * 64 + d];
            pooled[d] = s * (1.0f / 256.0f);
        }
        __syncthreads();
        if (tid < 64) {
            float a1 = mod_b1[n * HMOD + d];
            for (int q = 0; q < 64; ++q)
                a1 = fmaf(pooled[q], mod_w1[((size_t)n * 64 + q) * HMOD + d], a1);
            mh[d] = tanh_fast(a1);
        }
        __syncthreads();
        if (tid < 64) {
            float a2 = mod_b2[n * 64 + d];
            for (int q = 0; q < HMOD; ++q)
                a2 = fmaf(mh[q], mod_w2[((size_t)n * HMOD + q) * 64 + d], a2);
            gatep[n * 64 + d] = tanh_fast(a2);
        }
    }
}

// ---------- kernel 2: edge phase (v6: software-pipelined kp loop) ----------
// 256 blocks (half-cell) x 1024 thr (16 waves x 8 neurons as 4 pairs).
// y-table (64K) + att f16 (16K) + folded w2 frags (16K) in LDS. kp loop is
// 2-deep pipelined (named prefetch vars -> no scratch); next pair's conn/bews
// issued before current compute.

__global__ __launch_bounds__(1024, 4) void edge_kernel(
    const unsigned short* __restrict__ yws, const unsigned short* __restrict__ bews,
    const unsigned* __restrict__ att2, const int* __restrict__ conn_idx,
    const float* __restrict__ msg_w2, const float* __restrict__ msg_gs1,
    const float* __restrict__ msg_gb1, const float* __restrict__ msg_gs2,
    const float* __restrict__ msg_b2, const float* __restrict__ msg_gb2,
    const int* __restrict__ cell_to_group,
    unsigned short* __restrict__ aggws)
{
    __shared__ __align__(16) unsigned yl32[C_N * 64];                  // 64KB
    __shared__ __align__(16) unsigned attl[128 * 32];                  // 16KB
    __shared__ __align__(16) uint4 w2l[16 * 64];                       // 16KB
    __shared__ float mb2cl[64];                                        // 256B
    __shared__ __align__(16) unsigned short pbuf_all[16][8 * 128];     // 32KB
    __shared__ __align__(16) unsigned short aggT_all[16][2 * 64];      // 4KB
    int tid = threadIdx.x, bid = blockIdx.x;
    int n = bid >> 1;
    int wave = tid >> 6, lane = tid & 63;
    int lrow = lane & 15, lgrp = lane >> 4;
    int base = n * C_N + (bid & 1) * 128 + wave * 8;

    {
        const uint4* src = (const uint4*)((const char*)yws + (size_t)n * C_N * 256);
        uint4* dst = (uint4*)yl32;
        #pragma unroll
        for (int it = 0; it < 4; ++it) dst[it * 1024 + tid] = src[it * 1024 + tid];
        const uint4* asrc = (const uint4*)(att2 + ((size_t)n * 256 + (bid & 1) * 128) * 32);
        ((uint4*)attl)[tid] = asrc[tid];
    }
    if (wave == 0) {
        uint4 w2f[4][4];
        float mb2c[4];
        int g = cell_to_group[n];
        load_w2_folded(msg_w2, msg_gs1, msg_gb1, msg_gs2, msg_b2, msg_gb2,
                       g, lrow, lgrp, w2f, mb2c);
        #pragma unroll
        for (int t = 0; t < 4; ++t) {
            #pragma unroll
            for (int kf = 0; kf < 4; ++kf)
                w2l[(t * 4 + kf) * 64 + lane] = w2f[t][kf];
            if (lgrp == 0) mb2cl[t * 16 + lrow] = mb2c[t];
        }
    }
    __syncthreads();

    float mb2r0 = mb2cl[lrow], mb2r1 = mb2cl[16 + lrow],
          mb2r2 = mb2cl[32 + lrow], mb2r3 = mb2cl[48 + lrow];
    char* pbuf_b = reinterpret_cast<char*>(pbuf_all[wave]);
    char* aggT_b = reinterpret_cast<char*>(aggT_all[wave]);
    const unsigned* bews32 = (const unsigned*)bews;

    // prefetch pair 0
    int jvA = conn_idx[(size_t)base * 16 + lrow];
    int jvB = conn_idx[(size_t)(base + 1) * 16 + lrow];
    unsigned bepA = bews32[(size_t)base * 64 + lane];
    unsigned bepB = bews32[(size_t)(base + 1) * 64 + lane];

    #pragma unroll 1
    for (int pr = 0; pr < 4; ++pr) {
        int gA = base + pr * 2;
        // issue next pair's global loads early (overlap with compute)
        int prn = (pr < 3) ? (pr + 1) : 3;
        int gAn = base + prn * 2;
        int jvA_n = conn_idx[(size_t)gAn * 16 + lrow];
        int jvB_n = conn_idx[(size_t)(gAn + 1) * 16 + lrow];
        unsigned bepA_n = bews32[(size_t)gAn * 64 + lane];
        unsigned bepB_n = bews32[(size_t)(gAn + 1) * 64 + lane];

        float beA0 = bflo(bepA), beA1 = bfhi(bepA);
        float beB0 = bflo(bepB), beB1 = bfhi(bepB);
        int laA = wave * 8 + pr * 2, laB = laA + 1;

        float pA[4][2] = {{0.f,0.f},{0.f,0.f},{0.f,0.f},{0.f,0.f}};
        float pB[4][2] = {{0.f,0.f},{0.f,0.f},{0.f,0.f},{0.f,0.f}};

        // --- kp pipeline: preload kp=0 ---
        unsigned uyA0c, uyA1c, uyB0c, uyB1c;
        uint4 aqAc, aqBc;
        {
            int jA0 = __builtin_amdgcn_readlane(jvA, 0);
            int jA1 = __builtin_amdgcn_readlane(jvA, 1);
            int jB0 = __builtin_amdgcn_readlane(jvB, 0);
            int jB1 = __builtin_amdgcn_readlane(jvB, 1);
            uyA0c = yl32[jA0 * 64 + lane];
            uyA1c = yl32[jA1 * 64 + lane];
            uyB0c = yl32[jB0 * 64 + lane];
            uyB1c = yl32[jB1 * 64 + lane];
            aqAc = *reinterpret_cast<const uint4*>(&attl[laA * 32]);
            aqBc = *reinterpret_cast<const uint4*>(&attl[laB * 32]);
        }

        #pragma unroll
        for (int kp = 0; kp < 8; ++kp) {
            unsigned uyA0n, uyA1n, uyB0n, uyB1n;
            uint4 aqAn2, aqBn2;
            if (kp < 7) {
                int jA0 = __builtin_amdgcn_readlane(jvA, 2 * kp + 2);
                int jA1 = __builtin_amdgcn_readlane(jvA, 2 * kp + 3);
                int jB0 = __builtin_amdgcn_readlane(jvB, 2 * kp + 2);
                int jB1 = __builtin_amdgcn_readlane(jvB, 2 * kp + 3);
                uyA0n = yl32[jA0 * 64 + lane];
                uyA1n = yl32[jA1 * 64 + lane];
                uyB0n = yl32[jB0 * 64 + lane];
                uyB1n = yl32[jB1 * 64 + lane];
                aqAn2 = *reinterpret_cast<const uint4*>(&attl[laA * 32 + (kp + 1) * 4]);
                aqBn2 = *reinterpret_cast<const uint4*>(&attl[laB * 32 + (kp + 1) * 4]);
            }

            float gA00 = sgelu(bflo(uyA0c) + beA0), gA01 = sgelu(bfhi(uyA0c) + beA1);
            float gA10 = sgelu(bflo(uyA1c) + beA0), gA11 = sgelu(bfhi(uyA1c) + beA1);
            float gB00 = sgelu(bflo(uyB0c) + beB0), gB01 = sgelu(bfhi(uyB0c) + beB1);
            float gB10 = sgelu(bflo(uyB1c) + beB0), gB11 = sgelu(bfhi(uyB1c) + beB1);
            half2_t GA0 = pkrtz(gA00, gA10);
            half2_t GA1 = pkrtz(gA01, gA11);
            half2_t GB0 = pkrtz(gB00, gB10);
            half2_t GB1 = pkrtz(gB01, gB11);

            half2_t hA, hB;
            hA = h2(aqAc.x); hB = h2(aqBc.x);
            pA[0][0] = __builtin_amdgcn_fdot2(GA0, hA, pA[0][0], false);
            pA[0][1] = __builtin_amdgcn_fdot2(GA1, hA, pA[0][1], false);
            pB[0][0] = __builtin_amdgcn_fdot2(GB0, hB, pB[0][0], false);
            pB[0][1] = __builtin_amdgcn_fdot2(GB1, hB, pB[0][1], false);
            hA = h2(aqAc.y); hB = h2(aqBc.y);
            pA[1][0] = __builtin_amdgcn_fdot2(GA0, hA, pA[1][0], false);
            pA[1][1] = __builtin_amdgcn_fdot2(GA1, hA, pA[1][1], false);
            pB[1][0] = __builtin_amdgcn_fdot2(GB0, hB, pB[1][0], false);
            pB[1][1] = __builtin_amdgcn_fdot2(GB1, hB, pB[1][1], false);
            hA = h2(aqAc.z); hB = h2(aqBc.z);
            pA[2][0] = __builtin_amdgcn_fdot2(GA0, hA, pA[2][0], false);
            pA[2][1] = __builtin_amdgcn_fdot2(GA1, hA, pA[2][1], false);
            pB[2][0] = __builtin_amdgcn_fdot2(GB0, hB, pB[2][0], false);
            pB[2][1] = __builtin_amdgcn_fdot2(GB1, hB, pB[2][1], false);
            hA = h2(aqAc.w); hB = h2(aqBc.w);
            pA[3][0] = __builtin_amdgcn_fdot2(GA0, hA, pA[3][0], false);
            pA[3][1] = __builtin_amdgcn_fdot2(GA1, hA, pA[3][1], false);
            pB[3][0] = __builtin_amdgcn_fdot2(GB0, hB, pB[3][0], false);
            pB[3][1] = __builtin_amdgcn_fdot2(GB1, hB, pB[3][1], false);

            if (kp < 7) {
                uyA0c = uyA0n; uyA1c = uyA1n; uyB0c = uyB0n; uyB1c = uyB1n;
                aqAc = aqAn2; aqBc = aqBn2;
            }
        }

        #pragma unroll
        for (int t = 0; t < 4; ++t) {
            int rowA = t * 2, rowB = rowA + 1;
            *reinterpret_cast<unsigned*>(
                pbuf_b + rowA * 256 + ((lane * 4) ^ ((rowA & 7) << 4))) =
                cvtpk(pA[t][0], pA[t][1]);
            *reinterpret_cast<unsigned*>(
                pbuf_b + rowB * 256 + ((lane * 4) ^ ((rowB & 7) << 4))) =
                cvtpk(pB[t][0], pB[t][1]);
        }

        #pragma unroll
        for (int t = 0; t < 4; ++t) {
            f32x4v acc = {0.f, 0.f, 0.f, 0.f};
            #pragma unroll
            for (int kf = 0; kf < 4; ++kf) {
                int row = t * 2 + (lrow & 1);
                uint4 a = *reinterpret_cast<const uint4*>(
                    pbuf_b + row * 256 + ((kf * 64 + lgrp * 16) ^ ((row & 7) << 4)));
                acc = mfma16(a, w2l[(t * 4 + kf) * 64 + lane], acc);
            }
            if (lgrp == 0) {
                float mb = (t == 0) ? mb2r0 : (t == 1) ? mb2r1 : (t == 2) ? mb2r2 : mb2r3;
                #pragma unroll
                for (int r = 0; r < 2; ++r) {
                    float v = acc[r] + mb;
                    int byte = r * 128 + ((((t * 16 + lrow)) * 2) ^ ((r & 7) << 4));
                    *reinterpret_cast<unsigned short*>(aggT_b + byte) = f2bf(v);
                }
            }
        }
        if (lane < 16) {
            int row = lane >> 3, col = lane & 7;
            int byte = row * 128 + ((col * 16) ^ ((row & 7) << 4));
            uint4 v = *reinterpret_cast<const uint4*>(aggT_b + byte);
            *reinterpret_cast<uint4*>(
                (char*)aggws + (size_t)(gA + row) * 128 + col * 16) = v;
        }
        jvA = jvA_n; jvB = jvB_n; bepA = bepA_n; bepB = bepB_n;
    }
}

// ---------- kernel 3: state MLP + residual ----------

__global__ __launch_bounds__(512, 4) void state_kernel(
    const float* __restrict__ h, const unsigned short* __restrict__ aggws,
    const float* __restrict__ gatep,
    const float* __restrict__ state_w1, const float* __restrict__ state_b1,
    const float* __restrict__ state_gs1, const float* __restrict__ state_gb1,
    const float* __restrict__ state_w2, const float* __restrict__ state_b2,
    const float* __restrict__ state_gs2, const float* __restrict__ state_gb2,
    const int* __restrict__ cell_to_group, float* __restrict__ out)
{
    __shared__ __align__(16) unsigned short w1s[128 * 128];      // 32KB
    __shared__ __align__(16) unsigned short s1b_all[8][16 * 128]; // 4KB/wave
    int tid = threadIdx.x, bid = blockIdx.x;
    int n = bid >> 1;
    int g = cell_to_group[n];

    for (int idx = tid; idx < 2048; idx += 512) {
        int row = idx >> 4, ch = idx & 15;
        uint4 p = packf8(state_w1 + (size_t)row * 128 + ch * 8);
        int byte = row * 256 + ((ch * 16) ^ ((row & 7) << 4));
        *reinterpret_cast<uint4*>(reinterpret_cast<char*>(w1s) + byte) = p;
    }
    __syncthreads();

    int wave = tid >> 6, lane = tid & 63;
    int lrow = lane & 15, lgrp = lane >> 4;
    int c0 = (bid & 1) * 128 + wave * 16;
    unsigned short* s1b = s1b_all[wave];

    uint4 sB[4];
    {
        const float* hp = h + ((size_t)n * C_N + c0 + lrow) * 64;
        sB[0] = packf8(hp + lgrp * 8);
        sB[1] = packf8(hp + 32 + lgrp * 8);
        const char* ap = (const char*)aggws + ((size_t)n * C_N + c0 + lrow) * 128;
        sB[2] = *reinterpret_cast<const uint4*>(ap + lgrp * 16);
        sB[3] = *reinterpret_cast<const uint4*>(ap + 64 + lgrp * 16);
    }
    for (int nbM = 0; nbM < 8; ++nbM) {
        uint4 wA[4];
        #pragma unroll
        for (int kf = 0; kf < 4; ++kf)
            wA[kf] = *reinterpret_cast<const uint4*>(
                reinterpret_cast<const char*>(w1s) +
                (nbM * 16 + lrow) * 256 + ((kf * 64 + lgrp * 16) ^ ((lrow & 7) << 4)));
        f32x4v acc = {0.f, 0.f, 0.f, 0.f};
        #pragma unroll
        for (int kf = 0; kf < 4; ++kf) acc = mfma16(wA[kf], sB[kf], acc);
        float4 b1q = *(const float4*)(state_b1 + nbM * 16 + lgrp * 4);
        float g0 = gelu_f(acc[0] + b1q.x), g1 = gelu_f(acc[1] + b1q.y);
        float g2 = gelu_f(acc[2] + b1q.z), g3 = gelu_f(acc[3] + b1q.w);
        uint2 pk = make_uint2(cvtpk(g0, g1), cvtpk(g2, g3));
        int byte = lrow * 256 + ((nbM * 32 + lgrp * 8) ^ ((lrow & 7) << 4));
        *reinterpret_cast<uint2*>(reinterpret_cast<char*>(s1b) + byte) = pk;
    }

    uint4 w2sf[4][4];
    float sb2c[4];
    load_w2_folded(state_w2, state_gs1, state_gb1, state_gs2, state_b2, state_gb2,
                   g, lrow, lgrp, w2sf, sb2c);
    uint4 s1A[4];
    #pragma unroll
    for (int kf = 0; kf < 4; ++kf)
        s1A[kf] = *reinterpret_cast<const uint4*>(
            reinterpret_cast<const char*>(s1b) +
            lrow * 256 + ((kf * 64 + lgrp * 16) ^ ((lrow & 7) << 4)));

    float* dT = reinterpret_cast<float*>(s1b);   // reuse 4KB as [16c][64d] f32
    #pragma unroll
    for (int nb2 = 0; nb2 < 4; ++nb2) {
        f32x4v acc = {0.f, 0.f, 0.f, 0.f};
        #pragma unroll
        for (int kf = 0; kf < 4; ++kf) acc = mfma16(s1A[kf], w2sf[nb2][kf], acc);
        #pragma unroll
        for (int r = 0; r < 4; ++r) {
            int c = lgrp * 4 + r;
            int d = nb2 * 16 + lrow;
            int byte = c * 256 + ((d * 4) ^ ((c & 7) << 4));
            *reinterpret_cast<float*>(reinterpret_cast<char*>(dT) + byte) = acc[r] + sb2c[nb2];
        }
    }
    #pragma unroll
    for (int pass = 0; pass < 4; ++pass) {
        int idx = pass * 64 + lane;
        int row = idx >> 4, col = idx & 15;
        int byte = row * 256 + ((col * 16) ^ ((row & 7) << 4));
        float4 dv = *reinterpret_cast<const float4*>(reinterpret_cast<const char*>(dT) + byte);
        size_t off = ((size_t)n * C_N + c0 + row) * 64 + col * 4;
        float4 hv = *(const float4*)(h + off);
        float4 gv = *(const float4*)(gatep + n * 64 + col * 4);
        float4 o;
        o.x = fmaf(gv.x, dv.x, hv.x);
        o.y = fmaf(gv.y, dv.y, hv.y);
        o.z = fmaf(gv.z, dv.z, hv.z);
        o.w = fmaf(gv.w, dv.w, hv.w);
        *(float4*)(out + off) = o;
    }
}

// ---------- launch ----------

extern "C" void kernel_launch(void* const* d_in, const int* in_sizes, int n_in,
                              void* d_out, int out_size, void* d_ws, size_t ws_size,
                              hipStream_t stream) {
    (void)in_sizes; (void)n_in; (void)out_size; (void)ws_size;
    const float* h          = (const float*)d_in[0];
    const float* neuron_id  = (const float*)d_in[1];
    const float* neuron_key = (const float*)d_in[2];
    const float* state_w1   = (const float*)d_in[3];
    const float* state_b1   = (const float*)d_in[4];
    const float* state_gs1  = (const float*)d_in[5];
    const float* state_gb1  = (const float*)d_in[6];
    const float* state_w2   = (const float*)d_in[7];
    const float* state_b2   = (const float*)d_in[8];
    const float* state_gs2  = (const float*)d_in[9];
    const float* state_gb2  = (const float*)d_in[10];
    const float* msg_w1     = (const float*)d_in[11];
    const float* msg_b1     = (const float*)d_in[12];
    const float* msg_gs1    = (const float*)d_in[13];
    const float* msg_gb1    = (const float*)d_in[14];
    const float* msg_w2     = (const float*)d_in[15];
    const float* msg_b2     = (const float*)d_in[16];
    const float* msg_gs2    = (const float*)d_in[17];
    const float* msg_gb2    = (const float*)d_in[18];
    const float* mod_w1     = (const float*)d_in[19];
    const float* mod_b1     = (const float*)d_in[20];
    const float* mod_w2     = (const float*)d_in[21];
    const float* mod_b2     = (const float*)d_in[22];
    const int*   conn_idx   = (const int*)d_in[23];
    const int*   c2g        = (const int*)d_in[24];

    char* ws = (char*)d_ws;
    float*          gatep = (float*)ws;                                        // 32 KB
    unsigned short* yws   = (unsigned short*)(ws + (32u << 10));               // 8 MB
    unsigned short* bews  = (unsigned short*)(ws + (32u << 10) + (8u << 20));  // 8 MB
    unsigned*       att2  = (unsigned*)(ws + (32u << 10) + (16u << 20));       // 4 MB
    unsigned short* aggws = (unsigned short*)(ws + (32u << 10) + (24u << 20)); // 4 MB
    float* outp = (float*)d_out;

    prep_kernel<<<dim3(640), dim3(512), 0, stream>>>(
        h, neuron_id, neuron_key, msg_w1, msg_b1,
        mod_w1, mod_b1, mod_w2, mod_b2, conn_idx,
        yws, bews, att2, gatep);
    edge_kernel<<<dim3(256), dim3(1024), 0, stream>>>(
        yws, bews, att2, conn_idx,
        msg_w2, msg_gs1, msg_gb1, msg_gs2, msg_b2, msg_gb2, c2g, aggws);
    state_kernel<<<dim3(256), dim3(512), 0, stream>>>(
        h, aggws, gatep,
        state_w1, state_b1, state_gs1, state_gb1,
        state_w2, state_b2, state_gs2, state_gb2, c2g, outp);
}

// Round 10
// 105.241 us; speedup vs baseline: 1.2942x; 1.0648x over previous
//
#include <hip/hip_runtime.h>
#include <hip/hip_bf16.h>

#define N_CELLS 128
#define C_N     256
#define K_NB    16
#define D_N     64
#define G_N     8
#define HS      128
#define HM      128
#define HMOD    64

typedef __bf16 bf16x8 __attribute__((ext_vector_type(8)));
typedef float  f32x4v __attribute__((ext_vector_type(4)));
typedef _Float16 half2_t __attribute__((ext_vector_type(2)));

// ---------- helpers ----------

__device__ __forceinline__ unsigned cvtpk(float lo, float hi) {
    __hip_bfloat162 t = __float22bfloat162_rn(float2{lo, hi});
    return *reinterpret_cast<unsigned*>(&t);
}

__device__ __forceinline__ unsigned short f2bf(float f) {
    return (unsigned short)(cvtpk(f, 0.f) & 0xffffu);
}

__device__ __forceinline__ float bflo(unsigned u) { return __uint_as_float(u << 16); }
__device__ __forceinline__ float bfhi(unsigned u) { return __uint_as_float(u & 0xffff0000u); }

__device__ __forceinline__ half2_t pkrtz(float lo, float hi) {
    return __builtin_bit_cast(half2_t, __builtin_amdgcn_cvt_pkrtz(lo, hi));
}

__device__ __forceinline__ half2_t h2(unsigned u) {
    return __builtin_bit_cast(half2_t, u);
}

__device__ __forceinline__ f32x4v mfma16(uint4 a, uint4 b, f32x4v c) {
    return __builtin_amdgcn_mfma_f32_16x16x32_bf16(
        __builtin_bit_cast(bf16x8, a), __builtin_bit_cast(bf16x8, b), c, 0, 0, 0);
}

__device__ __forceinline__ float gelu_f(float x) {      // exact tanh-gelu (node/state)
    float x2 = x * x;
    float u  = x * fmaf(x2, 0.044715f, 1.0f);
    float e  = __expf(1.5957691216057308f * u);
    float r  = __builtin_amdgcn_rcpf(e + 1.0f);
    return x - x * r;
}

__device__ __forceinline__ float sgelu(float x) {       // sigmoid-gelu (edge)
    float e = __expf(-1.702f * x);
    float r = __builtin_amdgcn_rcpf(e + 1.0f);
    return x * r;
}

__device__ __forceinline__ float tanh_fast(float z) {
    float e = __expf(2.0f * z);
    return 1.0f - 2.0f / (e + 1.0f);
}

__device__ __forceinline__ uint4 packf8(const float* p) {
    float4 a = *(const float4*)p, b = *(const float4*)(p + 4);
    return make_uint4(cvtpk(a.x, a.y), cvtpk(a.z, a.w), cvtpk(b.x, b.y), cvtpk(b.z, b.w));
}

// wf = gs2[d] * w2[d][k] * gs1[k];  c2 = gs2*(w2.gb1 + b2) + gb2   (verified R2)
__device__ __forceinline__ void load_w2_folded(
    const float* __restrict__ w2, const float* __restrict__ gs1,
    const float* __restrict__ gb1, const float* __restrict__ gs2,
    const float* __restrict__ b2, const float* __restrict__ gb2,
    int g, int lrow, int lgrp, uint4 wf[4][4], float c2[4])
{
    #pragma unroll
    for (int nb2 = 0; nb2 < 4; ++nb2) {
        int d = nb2 * 16 + lrow;
        float gs2d = gs2[g * 64 + d];
        float cgb = 0.0f;
        #pragma unroll
        for (int kf = 0; kf < 4; ++kf) {
            int k0 = kf * 32 + lgrp * 8;
            const float* wp = w2 + d * 128 + k0;
            float4 wa = *(const float4*)wp, wb = *(const float4*)(wp + 4);
            const float* gp = gs1 + g * 128 + k0;
            float4 ga = *(const float4*)gp, gbv = *(const float4*)(gp + 4);
            const float* bp = gb1 + g * 128 + k0;
            float4 ba = *(const float4*)bp, bbv = *(const float4*)(bp + 4);
            cgb += wa.x*ba.x + wa.y*ba.y + wa.z*ba.z + wa.w*ba.w
                 + wb.x*bbv.x + wb.y*bbv.y + wb.z*bbv.z + wb.w*bbv.w;
            wf[nb2][kf] = make_uint4(
                cvtpk(wa.x*ga.x*gs2d,  wa.y*ga.y*gs2d),
                cvtpk(wa.z*ga.z*gs2d,  wa.w*ga.w*gs2d),
                cvtpk(wb.x*gbv.x*gs2d, wb.y*gbv.y*gs2d),
                cvtpk(wb.z*gbv.z*gs2d, wb.w*gbv.w*gs2d));
        }
        cgb += __shfl_xor(cgb, 16);
        cgb += __shfl_xor(cgb, 32);
        c2[nb2] = fmaf(gs2d, cgb + b2[d], gb2[g * 64 + d]);
    }
}

// ---------- kernel 1: fused prep (node + att + gate), 640 blocks x 512 thr ----------

__global__ __launch_bounds__(512, 2) void prep_kernel(
    const float* __restrict__ h, const float* __restrict__ neuron_id,
    const float* __restrict__ neuron_key,
    const float* __restrict__ msg_w1, const float* __restrict__ msg_b1,
    const float* __restrict__ mod_w1, const float* __restrict__ mod_b1,
    const float* __restrict__ mod_w2, const float* __restrict__ mod_b2,
    const int* __restrict__ conn_idx,
    unsigned short* __restrict__ yws, unsigned short* __restrict__ bews,
    unsigned* __restrict__ att2, float* __restrict__ gatep)
{
    __shared__ __align__(16) unsigned short shmem[8][16 * 256];   // 64KB
    int tid = threadIdx.x, bid = blockIdx.x;
    int wave = tid >> 6, lane = tid & 63;
    int lrow = lane & 15, lgrp = lane >> 4;

    if (bid < 256) {
        // ---------------- node section ----------------
        int n = bid >> 1;
        int c0 = (bid & 1) * 128 + wave * 16;
        unsigned short* ybuf = shmem[wave];

        uint4 bf[2];
        {
            const float* hp = h + ((size_t)n * C_N + (c0 + lrow)) * 64;
            bf[0] = packf8(hp + lgrp * 8);
            bf[1] = packf8(hp + 32 + lgrp * 8);
        }
        for (int nbM = 0; nbM < 16; ++nbM) {
            int o = nbM * 16 + lrow;
            uint4 af[2];
            #pragma unroll
            for (int kf = 0; kf < 2; ++kf) {
                int k = kf * 32 + lgrp * 8;
                const float* wp = (o < 128) ? (msg_w1 + (size_t)o * 128 + k)
                                            : (msg_w1 + (size_t)(o - 128) * 128 + 64 + k);
                af[kf] = packf8(wp);
            }
            f32x4v acc = {0.f, 0.f, 0.f, 0.f};
            acc = mfma16(af[0], bf[0], acc);
            acc = mfma16(af[1], bf[1], acc);
            float4 addv = {0.f, 0.f, 0.f, 0.f};
            if (nbM >= 8) addv = *(const float4*)(msg_b1 + (nbM - 8) * 16 + lgrp * 4);
            uint2 pk = make_uint2(cvtpk(acc[0] + addv.x, acc[1] + addv.y),
                                  cvtpk(acc[2] + addv.z, acc[3] + addv.w));
            int byte = lrow * 512 + ((nbM * 32 + lgrp * 8) ^ ((lrow & 7) << 4));
            *reinterpret_cast<uint2*>(reinterpret_cast<char*>(ybuf) + byte) = pk;
        }
        #pragma unroll
        for (int pass = 0; pass < 8; ++pass) {
            int idx = pass * 64 + lane;
            int row = idx >> 5, col = idx & 31;
            int byte = row * 512 + ((col * 16) ^ ((row & 7) << 4));
            uint4 v = *reinterpret_cast<const uint4*>(
                reinterpret_cast<const char*>(ybuf) + byte);
            size_t rb = (((size_t)n * C_N + c0 + row) * 128) * 2;
            if (col < 16)
                *reinterpret_cast<uint4*>(reinterpret_cast<char*>(yws) + rb + col * 16) = v;
            else
                *reinterpret_cast<uint4*>(reinterpret_cast<char*>(bews) + rb + (col - 16) * 16) = v;
        }
    } else if (bid < 512) {
        // ---------------- attention section ----------------
        int t = lgrp;
        int base = (bid - 256) * 128 + wave * 16;
        for (int i = 0; i < 16; ++i) {
            int gidx = base + i;
            int jv = conn_idx[(size_t)gidx * 16 + lrow];
            const float* kp = neuron_id + ((size_t)(gidx & ~255) + jv) * 64 + t * 16;
            const float* qp = neuron_key + (size_t)gidx * 64 + t * 16;
            float4 k0 = *(const float4*)kp,       k1 = *(const float4*)(kp + 4),
                   k2 = *(const float4*)(kp + 8), k3 = *(const float4*)(kp + 12);
            float4 q0 = *(const float4*)qp,       q1 = *(const float4*)(qp + 4),
                   q2 = *(const float4*)(qp + 8), q3 = *(const float4*)(qp + 12);
            float dt = k0.x*q0.x + k0.y*q0.y + k0.z*q0.z + k0.w*q0.w
                     + k1.x*q1.x + k1.y*q1.y + k1.z*q1.z + k1.w*q1.w
                     + k2.x*q2.x + k2.y*q2.y + k2.z*q2.z + k2.w*q2.w
                     + k3.x*q3.x + k3.y*q3.y + k3.z*q3.z + k3.w*q3.w;
            float lg = dt * 0.25f;
            float mx = lg;
            mx = fmaxf(mx, __shfl_xor(mx, 1));
            mx = fmaxf(mx, __shfl_xor(mx, 2));
            mx = fmaxf(mx, __shfl_xor(mx, 4));
            mx = fmaxf(mx, __shfl_xor(mx, 8));
            float ex = __expf(lg - mx);
            float sm = ex;
            sm += __shfl_xor(sm, 1);
            sm += __shfl_xor(sm, 2);
            sm += __shfl_xor(sm, 4);
            sm += __shfl_xor(sm, 8);
            float av = ex * __builtin_amdgcn_rcpf(sm);
            float avn = __shfl_down(av, 1);
            if ((lrow & 1) == 0) {
                att2[(size_t)gidx * 32 + (lrow >> 1) * 4 + t] =
                    __builtin_bit_cast(unsigned, __builtin_amdgcn_cvt_pkrtz(av, avn));
            }
        }
    } else {
        // ---------------- gate section ----------------
        int n = bid - 512;
        float* red   = reinterpret_cast<float*>(shmem);     // [8][64]
        float* pooled = red + 8 * 64;
        float* mh     = pooled + 64;
        int d = lane, part = wave;
        const float* hn = h + (size_t)n * C_N * 64;
        float acc = 0.0f;
        #pragma unroll 4
        for (int i = 0; i < 32; ++i) acc += hn[(part * 32 + i) * 64 + d];
        red[part * 64 + d] = acc;
        __syncthreads();
        if (tid < 64) {
            float s = 0.0f;
            #pragma unroll
            for (int p = 0; p < 8; ++p) s += red[p * 64 + d];
            pooled[d] = s * (1.0f / 256.0f);
        }
        __syncthreads();
        if (tid < 64) {
            float a1 = mod_b1[n * HMOD + d];
            for (int q = 0; q < 64; ++q)
                a1 = fmaf(pooled[q], mod_w1[((size_t)n * 64 + q) * HMOD + d], a1);
            mh[d] = tanh_fast(a1);
        }
        __syncthreads();
        if (tid < 64) {
            float a2 = mod_b2[n * 64 + d];
            for (int q = 0; q < HMOD; ++q)
                a2 = fmaf(mh[q], mod_w2[((size_t)n * HMOD + q) * 64 + d], a2);
            gatep[n * 64 + d] = tanh_fast(a2);
        }
    }
}

// ---------- kernel 2: edge phase (v7: R8 body + waves_per_eu(4,4) -> 128 VGPR) ----------
// 256 blocks (half-cell) x 1024 thr (16 waves x 8 neurons as 4 pairs).
// LDS caps occupancy at 1 block/CU = 4 waves/EU; declaring (4,4) tells the
// compiler extra occupancy is impossible -> allocate up to 128 VGPRs, no spill.

__global__ __launch_bounds__(1024)
__attribute__((amdgpu_waves_per_eu(4, 4)))
void edge_kernel(
    const unsigned short* __restrict__ yws, const unsigned short* __restrict__ bews,
    const unsigned* __restrict__ att2, const int* __restrict__ conn_idx,
    const float* __restrict__ msg_w2, const float* __restrict__ msg_gs1,
    const float* __restrict__ msg_gb1, const float* __restrict__ msg_gs2,
    const float* __restrict__ msg_b2, const float* __restrict__ msg_gb2,
    const int* __restrict__ cell_to_group,
    unsigned short* __restrict__ aggws)
{
    __shared__ __align__(16) unsigned yl32[C_N * 64];                  // 64KB
    __shared__ __align__(16) unsigned attl[128 * 32];                  // 16KB
    __shared__ __align__(16) uint4 w2l[16 * 64];                       // 16KB
    __shared__ float mb2cl[64];                                        // 256B
    __shared__ __align__(16) unsigned short pbuf_all[16][8 * 128];     // 32KB
    __shared__ __align__(16) unsigned short aggT_all[16][2 * 64];      // 4KB
    int tid = threadIdx.x, bid = blockIdx.x;
    int n = bid >> 1;
    int wave = tid >> 6, lane = tid & 63;
    int lrow = lane & 15, lgrp = lane >> 4;
    int base = n * C_N + (bid & 1) * 128 + wave * 8;

    {
        const uint4* src = (const uint4*)((const char*)yws + (size_t)n * C_N * 256);
        uint4* dst = (uint4*)yl32;
        #pragma unroll
        for (int it = 0; it < 4; ++it) dst[it * 1024 + tid] = src[it * 1024 + tid];
        const uint4* asrc = (const uint4*)(att2 + ((size_t)n * 256 + (bid & 1) * 128) * 32);
        ((uint4*)attl)[tid] = asrc[tid];
    }
    if (wave == 0) {
        uint4 w2f[4][4];
        float mb2c[4];
        int g = cell_to_group[n];
        load_w2_folded(msg_w2, msg_gs1, msg_gb1, msg_gs2, msg_b2, msg_gb2,
                       g, lrow, lgrp, w2f, mb2c);
        #pragma unroll
        for (int t = 0; t < 4; ++t) {
            #pragma unroll
            for (int kf = 0; kf < 4; ++kf)
                w2l[(t * 4 + kf) * 64 + lane] = w2f[t][kf];
            if (lgrp == 0) mb2cl[t * 16 + lrow] = mb2c[t];
        }
    }
    __syncthreads();

    float mb2r0 = mb2cl[lrow], mb2r1 = mb2cl[16 + lrow],
          mb2r2 = mb2cl[32 + lrow], mb2r3 = mb2cl[48 + lrow];
    char* pbuf_b = reinterpret_cast<char*>(pbuf_all[wave]);
    char* aggT_b = reinterpret_cast<char*>(aggT_all[wave]);
    const unsigned* bews32 = (const unsigned*)bews;

    #pragma unroll 1
    for (int pr = 0; pr < 4; ++pr) {
        int gA = base + pr * 2, gB = gA + 1;
        int jvA = conn_idx[(size_t)gA * 16 + lrow];
        int jvB = conn_idx[(size_t)gB * 16 + lrow];
        unsigned bepA = bews32[(size_t)gA * 64 + lane];
        unsigned bepB = bews32[(size_t)gB * 64 + lane];
        float beA0 = bflo(bepA), beA1 = bfhi(bepA);
        float beB0 = bflo(bepB), beB1 = bfhi(bepB);
        int laA = wave * 8 + pr * 2, laB = laA + 1;

        float pA[4][2] = {{0.f,0.f},{0.f,0.f},{0.f,0.f},{0.f,0.f}};
        float pB[4][2] = {{0.f,0.f},{0.f,0.f},{0.f,0.f},{0.f,0.f}};

        #pragma unroll
        for (int kp = 0; kp < 8; ++kp) {
            int jA0 = __builtin_amdgcn_readlane(jvA, 2 * kp);
            int jA1 = __builtin_amdgcn_readlane(jvA, 2 * kp + 1);
            int jB0 = __builtin_amdgcn_readlane(jvB, 2 * kp);
            int jB1 = __builtin_amdgcn_readlane(jvB, 2 * kp + 1);
            unsigned uyA0 = yl32[jA0 * 64 + lane];
            unsigned uyA1 = yl32[jA1 * 64 + lane];
            unsigned uyB0 = yl32[jB0 * 64 + lane];
            unsigned uyB1 = yl32[jB1 * 64 + lane];
            uint4 aqA = *reinterpret_cast<const uint4*>(&attl[laA * 32 + kp * 4]);
            uint4 aqB = *reinterpret_cast<const uint4*>(&attl[laB * 32 + kp * 4]);

            float gA00 = sgelu(bflo(uyA0) + beA0), gA01 = sgelu(bfhi(uyA0) + beA1);
            float gA10 = sgelu(bflo(uyA1) + beA0), gA11 = sgelu(bfhi(uyA1) + beA1);
            float gB00 = sgelu(bflo(uyB0) + beB0), gB01 = sgelu(bfhi(uyB0) + beB1);
            float gB10 = sgelu(bflo(uyB1) + beB0), gB11 = sgelu(bfhi(uyB1) + beB1);
            half2_t GA0 = pkrtz(gA00, gA10);
            half2_t GA1 = pkrtz(gA01, gA11);
            half2_t GB0 = pkrtz(gB00, gB10);
            half2_t GB1 = pkrtz(gB01, gB11);

            half2_t hA, hB;
            hA = h2(aqA.x); hB = h2(aqB.x);
            pA[0][0] = __builtin_amdgcn_fdot2(GA0, hA, pA[0][0], false);
            pA[0][1] = __builtin_amdgcn_fdot2(GA1, hA, pA[0][1], false);
            pB[0][0] = __builtin_amdgcn_fdot2(GB0, hB, pB[0][0], false);
            pB[0][1] = __builtin_amdgcn_fdot2(GB1, hB, pB[0][1], false);
            hA = h2(aqA.y); hB = h2(aqB.y);
            pA[1][0] = __builtin_amdgcn_fdot2(GA0, hA, pA[1][0], false);
            pA[1][1] = __builtin_amdgcn_fdot2(GA1, hA, pA[1][1], false);
            pB[1][0] = __builtin_amdgcn_fdot2(GB0, hB, pB[1][0], false);
            pB[1][1] = __builtin_amdgcn_fdot2(GB1, hB, pB[1][1], false);
            hA = h2(aqA.z); hB = h2(aqB.z);
            pA[2][0] = __builtin_amdgcn_fdot2(GA0, hA, pA[2][0], false);
            pA[2][1] = __builtin_amdgcn_fdot2(GA1, hA, pA[2][1], false);
            pB[2][0] = __builtin_amdgcn_fdot2(GB0, hB, pB[2][0], false);
            pB[2][1] = __builtin_amdgcn_fdot2(GB1, hB, pB[2][1], false);
            hA = h2(aqA.w); hB = h2(aqB.w);
            pA[3][0] = __builtin_amdgcn_fdot2(GA0, hA, pA[3][0], false);
            pA[3][1] = __builtin_amdgcn_fdot2(GA1, hA, pA[3][1], false);
            pB[3][0] = __builtin_amdgcn_fdot2(GB0, hB, pB[3][0], false);
            pB[3][1] = __builtin_amdgcn_fdot2(GB1, hB, pB[3][1], false);
        }

        #pragma unroll
        for (int t = 0; t < 4; ++t) {
            int rowA = t * 2, rowB = rowA + 1;
            *reinterpret_cast<unsigned*>(
                pbuf_b + rowA * 256 + ((lane * 4) ^ ((rowA & 7) << 4))) =
                cvtpk(pA[t][0], pA[t][1]);
            *reinterpret_cast<unsigned*>(
                pbuf_b + rowB * 256 + ((lane * 4) ^ ((rowB & 7) << 4))) =
                cvtpk(pB[t][0], pB[t][1]);
        }

        #pragma unroll
        for (int t = 0; t < 4; ++t) {
            f32x4v acc = {0.f, 0.f, 0.f, 0.f};
            #pragma unroll
            for (int kf = 0; kf < 4; ++kf) {
                int row = t * 2 + (lrow & 1);
                uint4 a = *reinterpret_cast<const uint4*>(
                    pbuf_b + row * 256 + ((kf * 64 + lgrp * 16) ^ ((row & 7) << 4)));
                acc = mfma16(a, w2l[(t * 4 + kf) * 64 + lane], acc);
            }
            if (lgrp == 0) {
                float mb = (t == 0) ? mb2r0 : (t == 1) ? mb2r1 : (t == 2) ? mb2r2 : mb2r3;
                #pragma unroll
                for (int r = 0; r < 2; ++r) {
                    float v = acc[r] + mb;
                    int byte = r * 128 + ((((t * 16 + lrow)) * 2) ^ ((r & 7) << 4));
                    *reinterpret_cast<unsigned short*>(aggT_b + byte) = f2bf(v);
                }
            }
        }
        if (lane < 16) {
            int row = lane >> 3, col = lane & 7;
            int byte = row * 128 + ((col * 16) ^ ((row & 7) << 4));
            uint4 v = *reinterpret_cast<const uint4*>(aggT_b + byte);
            *reinterpret_cast<uint4*>(
                (char*)aggws + (size_t)(gA + row) * 128 + col * 16) = v;
        }
    }
}

// ---------- kernel 3: state MLP + residual ----------

__global__ __launch_bounds__(512, 4) void state_kernel(
    const float* __restrict__ h, const unsigned short* __restrict__ aggws,
    const float* __restrict__ gatep,
    const float* __restrict__ state_w1, const float* __restrict__ state_b1,
    const float* __restrict__ state_gs1, const float* __restrict__ state_gb1,
    const float* __restrict__ state_w2, const float* __restrict__ state_b2,
    const float* __restrict__ state_gs2, const float* __restrict__ state_gb2,
    const int* __restrict__ cell_to_group, float* __restrict__ out)
{
    __shared__ __align__(16) unsigned short w1s[128 * 128];      // 32KB
    __shared__ __align__(16) unsigned short s1b_all[8][16 * 128]; // 4KB/wave
    int tid = threadIdx.x, bid = blockIdx.x;
    int n = bid >> 1;
    int g = cell_to_group[n];

    for (int idx = tid; idx < 2048; idx += 512) {
        int row = idx >> 4, ch = idx & 15;
        uint4 p = packf8(state_w1 + (size_t)row * 128 + ch * 8);
        int byte = row * 256 + ((ch * 16) ^ ((row & 7) << 4));
        *reinterpret_cast<uint4*>(reinterpret_cast<char*>(w1s) + byte) = p;
    }
    __syncthreads();

    int wave = tid >> 6, lane = tid & 63;
    int lrow = lane & 15, lgrp = lane >> 4;
    int c0 = (bid & 1) * 128 + wave * 16;
    unsigned short* s1b = s1b_all[wave];

    uint4 sB[4];
    {
        const float* hp = h + ((size_t)n * C_N + c0 + lrow) * 64;
        sB[0] = packf8(hp + lgrp * 8);
        sB[1] = packf8(hp + 32 + lgrp * 8);
        const char* ap = (const char*)aggws + ((size_t)n * C_N + c0 + lrow) * 128;
        sB[2] = *reinterpret_cast<const uint4*>(ap + lgrp * 16);
        sB[3] = *reinterpret_cast<const uint4*>(ap + 64 + lgrp * 16);
    }
    for (int nbM = 0; nbM < 8; ++nbM) {
        uint4 wA[4];
        #pragma unroll
        for (int kf = 0; kf < 4; ++kf)
            wA[kf] = *reinterpret_cast<const uint4*>(
                reinterpret_cast<const char*>(w1s) +
                (nbM * 16 + lrow) * 256 + ((kf * 64 + lgrp * 16) ^ ((lrow & 7) << 4)));
        f32x4v acc = {0.f, 0.f, 0.f, 0.f};
        #pragma unroll
        for (int kf = 0; kf < 4; ++kf) acc = mfma16(wA[kf], sB[kf], acc);
        float4 b1q = *(const float4*)(state_b1 + nbM * 16 + lgrp * 4);
        float g0 = gelu_f(acc[0] + b1q.x), g1 = gelu_f(acc[1] + b1q.y);
        float g2 = gelu_f(acc[2] + b1q.z), g3 = gelu_f(acc[3] + b1q.w);
        uint2 pk = make_uint2(cvtpk(g0, g1), cvtpk(g2, g3));
        int byte = lrow * 256 + ((nbM * 32 + lgrp * 8) ^ ((lrow & 7) << 4));
        *reinterpret_cast<uint2*>(reinterpret_cast<char*>(s1b) + byte) = pk;
    }

    uint4 w2sf[4][4];
    float sb2c[4];
    load_w2_folded(state_w2, state_gs1, state_gb1, state_gs2, state_b2, state_gb2,
                   g, lrow, lgrp, w2sf, sb2c);
    uint4 s1A[4];
    #pragma unroll
    for (int kf = 0; kf < 4; ++kf)
        s1A[kf] = *reinterpret_cast<const uint4*>(
            reinterpret_cast<const char*>(s1b) +
            lrow * 256 + ((kf * 64 + lgrp * 16) ^ ((lrow & 7) << 4)));

    float* dT = reinterpret_cast<float*>(s1b);   // reuse 4KB as [16c][64d] f32
    #pragma unroll
    for (int nb2 = 0; nb2 < 4; ++nb2) {
        f32x4v acc = {0.f, 0.f, 0.f, 0.f};
        #pragma unroll
        for (int kf = 0; kf < 4; ++kf) acc = mfma16(s1A[kf], w2sf[nb2][kf], acc);
        #pragma unroll
        for (int r = 0; r < 4; ++r) {
            int c = lgrp * 4 + r;
            int d = nb2 * 16 + lrow;
            int byte = c * 256 + ((d * 4) ^ ((c & 7) << 4));
            *reinterpret_cast<float*>(reinterpret_cast<char*>(dT) + byte) = acc[r] + sb2c[nb2];
        }
    }
    #pragma unroll
    for (int pass = 0; pass < 4; ++pass) {
        int idx = pass * 64 + lane;
        int row = idx >> 4, col = idx & 15;
        int byte = row * 256 + ((col * 16) ^ ((row & 7) << 4));
        float4 dv = *reinterpret_cast<const float4*>(reinterpret_cast<const char*>(dT) + byte);
        size_t off = ((size_t)n * C_N + c0 + row) * 64 + col * 4;
        float4 hv = *(const float4*)(h + off);
        float4 gv = *(const float4*)(gatep + n * 64 + col * 4);
        float4 o;
        o.x = fmaf(gv.x, dv.x, hv.x);
        o.y = fmaf(gv.y, dv.y, hv.y);
        o.z = fmaf(gv.z, dv.z, hv.z);
        o.w = fmaf(gv.w, dv.w, hv.w);
        *(float4*)(out + off) = o;
    }
}

// ---------- launch ----------

extern "C" void kernel_launch(void* const* d_in, const int* in_sizes, int n_in,
                              void* d_out, int out_size, void* d_ws, size_t ws_size,
                              hipStream_t stream) {
    (void)in_sizes; (void)n_in; (void)out_size; (void)ws_size;
    const float* h          = (const float*)d_in[0];
    const float* neuron_id  = (const float*)d_in[1];
    const float* neuron_key = (const float*)d_in[2];
    const float* state_w1   = (const float*)d_in[3];
    const float* state_b1   = (const float*)d_in[4];
    const float* state_gs1  = (const float*)d_in[5];
    const float* state_gb1  = (const float*)d_in[6];
    const float* state_w2   = (const float*)d_in[7];
    const float* state_b2   = (const float*)d_in[8];
    const float* state_gs2  = (const float*)d_in[9];
    const float* state_gb2  = (const float*)d_in[10];
    const float* msg_w1     = (const float*)d_in[11];
    const float* msg_b1     = (const float*)d_in[12];
    const float* msg_gs1    = (const float*)d_in[13];
    const float* msg_gb1    = (const float*)d_in[14];
    const float* msg_w2     = (const float*)d_in[15];
    const float* msg_b2     = (const float*)d_in[16];
    const float* msg_gs2    = (const float*)d_in[17];
    const float* msg_gb2    = (const float*)d_in[18];
    const float* mod_w1     = (const float*)d_in[19];
    const float* mod_b1     = (const float*)d_in[20];
    const float* mod_w2     = (const float*)d_in[21];
    const float* mod_b2     = (const float*)d_in[22];
    const int*   conn_idx   = (const int*)d_in[23];
    const int*   c2g        = (const int*)d_in[24];

    char* ws = (char*)d_ws;
    float*          gatep = (float*)ws;                                        // 32 KB
    unsigned short* yws   = (unsigned short*)(ws + (32u << 10));               // 8 MB
    unsigned short* bews  = (unsigned short*)(ws + (32u << 10) + (8u << 20));  // 8 MB
    unsigned*       att2  = (unsigned*)(ws + (32u << 10) + (16u << 20));       // 4 MB
    unsigned short* aggws = (unsigned short*)(ws + (32u << 10) + (24u << 20)); // 4 MB
    float* outp = (float*)d_out;

    prep_kernel<<<dim3(640), dim3(512), 0, stream>>>(
        h, neuron_id, neuron_key, msg_w1, msg_b1,
        mod_w1, mod_b1, mod_w2, mod_b2, conn_idx,
        yws, bews, att2, gatep);
    edge_kernel<<<dim3(256), dim3(1024), 0, stream>>>(
        yws, bews, att2, conn_idx,
        msg_w2, msg_gs1, msg_gb1, msg_gs2, msg_b2, msg_gb2, c2g, aggws);
    state_kernel<<<dim3(256), dim3(512), 0, stream>>>(
        h, aggws, gatep,
        state_w1, state_b1, state_gs1, state_gb1,
        state_w2, state_b2, state_gs2, state_gb2, c2g, outp);
}